// Round 5
// baseline (245.712 us; speedup 1.0000x reference)
//
#include <hip/hip_runtime.h>
#include <math.h>

#define TN 2048            // T
#define NF 4096            // Bluestein FFT length
#define NB 64              // batch
#define LF 6142LL          // L = 3T-2
#define L2F 12284LL        // 2L
#define PI_D 3.14159265358979323846264338327950288
#define C8 0.70710678118654752440084436210485
#define K16A 0.92387953251128675612818318939678828682   // cos(pi/8)
#define K16B 0.38268343236508977172845998403039886676   // sin(pi/8)

typedef double2 cpx;

__device__ __forceinline__ cpx cmk(double a, double b){ cpx r; r.x=a; r.y=b; return r; }
__device__ __forceinline__ cpx cadd(cpx a, cpx b){ return cmk(a.x+b.x, a.y+b.y); }
__device__ __forceinline__ cpx csub(cpx a, cpx b){ return cmk(a.x-b.x, a.y-b.y); }
__device__ __forceinline__ cpx cmul(cpx a, cpx b){ return cmk(a.x*b.x - a.y*b.y, a.x*b.y + a.y*b.x); }
__device__ __forceinline__ cpx cmulc(cpx a, cpx b){ return cmk(a.x*b.x + a.y*b.y, a.y*b.x - a.x*b.y); } // a*conj(b)

// LDS swizzle (cpx granularity, involution)
__device__ __forceinline__ int SW(int i){ return i ^ ((i >> 3) & 7) ^ ((i >> 6) & 7); }

// wave-local sync: fences compiler + drains lgkmcnt; no cross-wave lock-step
__device__ __forceinline__ void wsync(){
  __builtin_amdgcn_wave_barrier();
  asm volatile("s_waitcnt lgkmcnt(0)" ::: "memory");
  __builtin_amdgcn_wave_barrier();
}

// ---------- 8-point register FFT (DIF, natural in; reg q holds freq R8[q]={0,4,2,6,1,5,3,7})
__device__ __forceinline__ void fft8_bc(cpx* a){
  cpx u, v, d;
  u=a[0]; v=a[2]; a[0]=cadd(u,v); a[2]=csub(u,v);
  u=a[1]; v=a[3]; a[1]=cadd(u,v); d=csub(u,v); a[3]=cmk(d.y, -d.x);
  u=a[4]; v=a[6]; a[4]=cadd(u,v); a[6]=csub(u,v);
  u=a[5]; v=a[7]; a[5]=cadd(u,v); d=csub(u,v); a[7]=cmk(d.y, -d.x);
  u=a[0]; v=a[1]; a[0]=cadd(u,v); a[1]=csub(u,v);
  u=a[2]; v=a[3]; a[2]=cadd(u,v); a[3]=csub(u,v);
  u=a[4]; v=a[5]; a[4]=cadd(u,v); a[5]=csub(u,v);
  u=a[6]; v=a[7]; a[6]=cadd(u,v); a[7]=csub(u,v);
}
__device__ __forceinline__ void fft8(cpx* a){
  cpx u, v, d;
  u=a[0]; v=a[4]; a[0]=cadd(u,v); a[4]=csub(u,v);
  u=a[1]; v=a[5]; a[1]=cadd(u,v); d=csub(u,v); a[5]=cmk(C8*(d.x+d.y), C8*(d.y-d.x));
  u=a[2]; v=a[6]; a[2]=cadd(u,v); d=csub(u,v); a[6]=cmk(d.y, -d.x);
  u=a[3]; v=a[7]; a[3]=cadd(u,v); d=csub(u,v); a[7]=cmk(C8*(d.y-d.x), -C8*(d.x+d.y));
  fft8_bc(a);
}
// unscaled inverse (input in fft8 reg order, output natural, x8)
__device__ __forceinline__ void ifft8(cpx* a){
  cpx u, v, t;
  u=a[0]; v=a[1]; a[0]=cadd(u,v); a[1]=csub(u,v);
  u=a[2]; v=a[3]; a[2]=cadd(u,v); a[3]=csub(u,v);
  u=a[4]; v=a[5]; a[4]=cadd(u,v); a[5]=csub(u,v);
  u=a[6]; v=a[7]; a[6]=cadd(u,v); a[7]=csub(u,v);
  u=a[0]; v=a[2]; a[0]=cadd(u,v); a[2]=csub(u,v);
  u=a[1]; t=a[3]; v=cmk(-t.y, t.x); a[1]=cadd(u,v); a[3]=csub(u,v);
  u=a[4]; v=a[6]; a[4]=cadd(u,v); a[6]=csub(u,v);
  u=a[5]; t=a[7]; v=cmk(-t.y, t.x); a[5]=cadd(u,v); a[7]=csub(u,v);
  u=a[0]; v=a[4]; a[0]=cadd(u,v); a[4]=csub(u,v);
  u=a[1]; t=a[5]; v=cmk(C8*(t.x-t.y), C8*(t.x+t.y)); a[1]=cadd(u,v); a[5]=csub(u,v);
  u=a[2]; t=a[6]; v=cmk(-t.y, t.x); a[2]=cadd(u,v); a[6]=csub(u,v);
  u=a[3]; t=a[7]; v=cmk(-C8*(t.x+t.y), C8*(t.x-t.y)); a[3]=cadd(u,v); a[7]=csub(u,v);
}

// ---------- 16-point register FFT: W16 level (stride 8) + two fft8.
// Output reg q holds freq R16[q] = 2*R8[q&7] + (q>>3) = bitrev4(q).
__device__ __forceinline__ void fft16(cpx* a){
  cpx u, v, d;
  u=a[0]; v=a[8];  a[0]=cadd(u,v); a[8] = csub(u,v);
  u=a[1]; v=a[9];  a[1]=cadd(u,v); d=csub(u,v); a[9]  = cmk(K16A*d.x + K16B*d.y, K16A*d.y - K16B*d.x);
  u=a[2]; v=a[10]; a[2]=cadd(u,v); d=csub(u,v); a[10] = cmk(C8*(d.x+d.y), C8*(d.y-d.x));
  u=a[3]; v=a[11]; a[3]=cadd(u,v); d=csub(u,v); a[11] = cmk(K16B*d.x + K16A*d.y, K16B*d.y - K16A*d.x);
  u=a[4]; v=a[12]; a[4]=cadd(u,v); d=csub(u,v); a[12] = cmk(d.y, -d.x);
  u=a[5]; v=a[13]; a[5]=cadd(u,v); d=csub(u,v); a[13] = cmk(K16A*d.y - K16B*d.x, -(K16A*d.x + K16B*d.y));
  u=a[6]; v=a[14]; a[6]=cadd(u,v); d=csub(u,v); a[14] = cmk(C8*(d.y-d.x), -C8*(d.x+d.y));
  u=a[7]; v=a[15]; a[7]=cadd(u,v); d=csub(u,v); a[15] = cmk(K16B*d.y - K16A*d.x, -(K16A*d.y + K16B*d.x));
  fft8(a); fft8(a+8);
}
// upper-half-zero input (a[8..15] implied 0): lvl1 degenerates to a[j+8]=a[j]*W16^j
__device__ __forceinline__ void fft16h(cpx* a){
  a[8]  = a[0];
  a[9]  = cmk(K16A*a[1].x + K16B*a[1].y, K16A*a[1].y - K16B*a[1].x);
  a[10] = cmk(C8*(a[2].x+a[2].y), C8*(a[2].y-a[2].x));
  a[11] = cmk(K16B*a[3].x + K16A*a[3].y, K16B*a[3].y - K16A*a[3].x);
  a[12] = cmk(a[4].y, -a[4].x);
  a[13] = cmk(K16A*a[5].y - K16B*a[5].x, -(K16A*a[5].x + K16B*a[5].y));
  a[14] = cmk(C8*(a[6].y-a[6].x), -C8*(a[6].x+a[6].y));
  a[15] = cmk(K16B*a[7].y - K16A*a[7].x, -(K16A*a[7].y + K16B*a[7].x));
  fft8(a); fft8(a+8);
}
// unscaled inverse (input fft16 reg order, output natural, x16):
// two ifft8 (x8 each) then undo W16 level with conj twiddles.
__device__ __forceinline__ void ifft16(cpx* a){
  ifft8(a); ifft8(a+8);
  cpx t, E;
  E=a[0]; t=a[8];                                                                 a[0]=cadd(E,t); a[8] =csub(E,t);
  E=a[1]; t=cmk(K16A*a[9].x - K16B*a[9].y,  K16A*a[9].y + K16B*a[9].x);           a[1]=cadd(E,t); a[9] =csub(E,t);
  E=a[2]; t=cmk(C8*(a[10].x - a[10].y),     C8*(a[10].x + a[10].y));              a[2]=cadd(E,t); a[10]=csub(E,t);
  E=a[3]; t=cmk(K16B*a[11].x - K16A*a[11].y, K16B*a[11].y + K16A*a[11].x);        a[3]=cadd(E,t); a[11]=csub(E,t);
  E=a[4]; t=cmk(-a[12].y, a[12].x);                                               a[4]=cadd(E,t); a[12]=csub(E,t);
  E=a[5]; t=cmk(-(K16B*a[13].x) - K16A*a[13].y, K16A*a[13].x - K16B*a[13].y);     a[5]=cadd(E,t); a[13]=csub(E,t);
  E=a[6]; t=cmk(-C8*(a[14].x + a[14].y),    C8*(a[14].x - a[14].y));              a[6]=cadd(E,t); a[14]=csub(E,t);
  E=a[7]; t=cmk(-(K16A*a[15].x) - K16B*a[15].y, K16B*a[15].x - K16A*a[15].y);     a[7]=cadd(E,t); a[15]=csub(E,t);
}
// pruned: only outputs a[0..7] (skip subtract half of the W16-undo level)
__device__ __forceinline__ void ifft16h(cpx* a){
  ifft8(a); ifft8(a+8);
  cpx t;
  t=a[8];                                                                 a[0]=cadd(a[0],t);
  t=cmk(K16A*a[9].x - K16B*a[9].y,  K16A*a[9].y + K16B*a[9].x);           a[1]=cadd(a[1],t);
  t=cmk(C8*(a[10].x - a[10].y),     C8*(a[10].x + a[10].y));              a[2]=cadd(a[2],t);
  t=cmk(K16B*a[11].x - K16A*a[11].y, K16B*a[11].y + K16A*a[11].x);        a[3]=cadd(a[3],t);
  t=cmk(-a[12].y, a[12].x);                                               a[4]=cadd(a[4],t);
  t=cmk(-(K16B*a[13].x) - K16A*a[13].y, K16A*a[13].x - K16B*a[13].y);     a[5]=cadd(a[5],t);
  t=cmk(-C8*(a[14].x + a[14].y),    C8*(a[14].x - a[14].y));              a[6]=cadd(a[6],t);
  t=cmk(-(K16A*a[15].x) - K16B*a[15].y, K16B*a[15].x - K16A*a[15].y);     a[7]=cadd(a[7],t);
}
// 4-point DIF; reg q holds freq R4[q] = {0,2,1,3}
__device__ __forceinline__ void fft4(cpx* a){
  cpx u, v, d;
  u=a[0]; v=a[2]; a[0]=cadd(u,v); a[2]=csub(u,v);
  u=a[1]; v=a[3]; a[1]=cadd(u,v); d=csub(u,v); a[3]=cmk(d.y, -d.x);
  u=a[0]; v=a[1]; a[0]=cadd(u,v); a[1]=csub(u,v);
  u=a[2]; v=a[3]; a[2]=cadd(u,v); a[3]=csub(u,v);
}

// ---------- K1: filters + tables
__global__ __launch_bounds__(256) void k_prep(
    const float* fw1, const float* fb1, const float* fw2, const float* fb2,
    const float* gw1, const float* gb1, const float* gw2, const float* gb2,
    const float* pw1, const float* pb1, const float* pw2, const float* pb2,
    const float* qw1, const float* qb1, const float* qw2, const float* qb2,
    double* arr, cpx* tw, cpx* Q, cpx* g2)
{
  int gid = blockIdx.x * 256 + threadIdx.x;   // < 8192
  if (gid < 4096){
    double s, c;
    sincos(-2.0 * PI_D * (double)gid / 4096.0, &s, &c);
    tw[gid] = cmk(c, s);
  }
  if (gid < 2048){
    long long i = gid;
    double s, c;
    long long a = ((2LL * TN - 2) * i) % LF;
    long long b = (i * i) % L2F;
    long long comb = (2 * a + b) % L2F;
    sincos(PI_D * (double)comb / (double)LF, &s, &c);
    Q[gid] = cmk(c, s);
    long long a2 = ((2LL * TN - 2 + i) * (TN - 1)) % LF;
    long long comb2 = (2 * a2 + b) % L2F;
    double phi = PI_D * (double)comb2 / (double)LF;
    double scale = 1.0 / ((double)LF * (double)LF) / (4096.0 * 4096.0);
    sincos(2.0 * phi, &s, &c);
    g2[gid] = cmk(c * scale, s * scale);
  }
  int fid = gid >> 11;
  int m = gid & (TN - 1);
  const float *W1, *B1, *W2, *B2;
  if (fid == 0){ W1=fw1; B1=fb1; W2=fw2; B2=fb2; }
  else if (fid == 1){ W1=gw1; B1=gb1; W2=gw2; B2=gb2; }
  else if (fid == 2){ W1=pw1; B1=pb1; W2=pw2; B2=pb2; }
  else { W1=qw1; B1=qb1; W2=qw2; B2=qb2; }
  int s = (fid == 0 || fid == 2) ? (TN - 1 - m) : m;
  double sv = (double)s;
  double z = (double)B2[0];
  #pragma unroll
  for (int h = 0; h < 5; h++)
    z += (double)W2[h] * tanh(sv * (double)W1[h] + (double)B1[h]);
  arr[fid * TN + m] = z * exp(-5.0 * sv);
}

// ---------- SO(3) helpers
__device__ __forceinline__ void mat_mul3(double* D, const double* A, const double* B){
  double r[9];
  #pragma unroll
  for (int i = 0; i < 3; i++)
    #pragma unroll
    for (int j = 0; j < 3; j++)
      r[i*3+j] = A[i*3]*B[j] + A[i*3+1]*B[3+j] + A[i*3+2]*B[6+j];
  #pragma unroll
  for (int k = 0; k < 9; k++) D[k] = r[k];
}
__device__ __forceinline__ void rod3(double* M, const double* a1, const double* a2,
                                     double z1, double z2){
  double G[9];
  #pragma unroll
  for (int k = 0; k < 9; k++) G[k] = a1[k]*z1 + a2[k]*z2;
  double wx = G[7], wy = G[2], wz = G[3];
  double th2 = wx*wx + wy*wy + wz*wz;
  double sa, cb;
  if (th2 < 1e-12){ sa = 1.0 - th2/6.0; cb = 0.5 - th2/24.0; }
  else { double th = sqrt(th2); sa = sin(th)/th; cb = (1.0 - cos(th))/th2; }
  double w[3] = {wx, wy, wz};
  #pragma unroll
  for (int i = 0; i < 3; i++)
    #pragma unroll
    for (int j = 0; j < 3; j++){
      double v = sa * G[i*3+j] + cb * (w[i]*w[j]);
      if (i == j) v += 1.0 - cb * th2;
      M[i*3+j] = v;
    }
}

// ---------- K2 merged: blocks 0-255 = H spectra (xQ folded), 256-319 = SO(3) scan, 320 = chat
__global__ __launch_bounds__(256) void k_front(
    const float* x, const float* A1f, const float* A2f,
    const double* arr, const cpx* Q, const cpx* tw,
    cpx* HsQ, double* Asc, cpx* chatp)
{
  __shared__ double smem[8192];   // 64 KB union
  int tid = threadIdx.x;
  int bid = blockIdx.x;
  if (bid < 256){
    cpx* part = (cpx*)smem;
    int f = bid >> 6;
    int jbase = (bid & 63) * 32;
    int chunk = tid & 7;
    int jl = tid >> 3;
    long long j = jbase + jl;
    long long jj = j + TN - 1;
    double s, c;
    sincos(-2.0 * PI_D * (double)jj / (double)LF, &s, &c);
    cpx W = cmk(c, s);
    long long m0 = (long long)chunk * 256;
    long long p0 = ((m0 + TN - 1) * jj) % LF;
    sincos(-2.0 * PI_D * (double)p0 / (double)LF, &s, &c);
    cpx ph = cmk(c, s);
    const double* a = arr + f * TN;
    cpx acc = cmk(0.0, 0.0);
    for (int m = (int)m0; m < (int)m0 + 256; m++){
      double av = a[m];
      acc.x += av * ph.x;
      acc.y += av * ph.y;
      ph = cmul(ph, W);
    }
    part[tid] = acc;
    __syncthreads();
    if (chunk == 0){
      cpx tot = cmk(0.0, 0.0);
      for (int q = 0; q < 8; q++) tot = cadd(tot, part[(jl << 3) + q]);
      HsQ[f * TN + (int)j] = cmul(tot, Q[j]);
    }
  } else if (bid < 320){
    int b = bid - 256;
    double (*S)[9] = (double(*)[9])smem;
    int k = tid;
    double a1[9], a2[9];
    #pragma unroll
    for (int i = 0; i < 3; i++)
      #pragma unroll
      for (int j = 0; j < 3; j++){
        a1[i*3+j] = (double)A1f[i*3+j] - (double)A1f[j*3+i];
        a2[i*3+j] = (double)A2f[i*3+j] - (double)A2f[j*3+i];
      }
    const float* xb = x + (size_t)b * TN * 2;
    double C[9] = {1,0,0, 0,1,0, 0,0,1};
    for (int i = 0; i < 8; i++){
      int t = k * 8 + i;
      if (t >= 1){
        double M[9];
        rod3(M, a1, a2, (double)xb[2*t], (double)xb[2*t+1]);
        mat_mul3(C, C, M);
      }
    }
    #pragma unroll
    for (int q = 0; q < 9; q++) S[k][q] = C[q];
    __syncthreads();
    for (int ofs = 1; ofs < 256; ofs <<= 1){
      double Lm[9], Rm[9];
      bool act = (k >= ofs);
      if (act){
        #pragma unroll
        for (int q = 0; q < 9; q++){ Lm[q] = S[k-ofs][q]; Rm[q] = S[k][q]; }
      }
      __syncthreads();
      if (act){
        double P[9];
        mat_mul3(P, Lm, Rm);
        #pragma unroll
        for (int q = 0; q < 9; q++) S[k][q] = P[q];
      }
      __syncthreads();
    }
    double P[9];
    if (k == 0){
      P[0]=1; P[1]=0; P[2]=0; P[3]=0; P[4]=1; P[5]=0; P[6]=0; P[7]=0; P[8]=1;
    } else {
      #pragma unroll
      for (int q = 0; q < 9; q++) P[q] = S[k-1][q];
    }
    for (int i = 0; i < 8; i++){
      int t = k * 8 + i;
      if (t >= 1){
        double M[9];
        rod3(M, a1, a2, (double)xb[2*t], (double)xb[2*t+1]);
        mat_mul3(P, P, M);
      }
      #pragma unroll
      for (int q = 0; q < 9; q++)
        Asc[(((size_t)b * 9 + q) << 11) + t] = P[q];
    }
  } else {
    // ---- chat: radix-16^3 DIF of chirp (MUST match k_czt stage decomposition).
    // Stored as chatp[(digit16<<8) | group]: group = stride-1 block index.
    cpx* buf = (cpx*)smem;
    const int R16[16] = {0,8,4,12,2,10,6,14,1,9,5,13,3,11,7,15};
    for (int mq = tid; mq < NF; mq += 256){
      long long mm = (mq <= 2048) ? mq : (NF - mq);
      long long qq = (mm * mm) % L2F;
      double s, c;
      sincos(-PI_D * (double)qq / (double)LF, &s, &c);
      buf[SW(mq)] = cmk(c, s);
    }
    __syncthreads();
    // T1: stride 256
    {
      cpx a[16];
      #pragma unroll
      for (int k = 0; k < 16; k++) a[k] = buf[SW(tid + (k << 8))];
      fft16(a);
      #pragma unroll
      for (int q = 0; q < 16; q++){
        int d = R16[q]; cpx v = a[q];
        if (d) v = cmul(v, tw[tid * d]);
        buf[SW(tid + (d << 8))] = v;
      }
    }
    __syncthreads();
    // T2: stride 16
    {
      int m2 = tid & 15, base2 = ((tid >> 4) << 8) + m2;
      cpx a[16];
      #pragma unroll
      for (int k = 0; k < 16; k++) a[k] = buf[SW(base2 + (k << 4))];
      fft16(a);
      #pragma unroll
      for (int q = 0; q < 16; q++){
        int d = R16[q]; cpx v = a[q];
        if (d) v = cmul(v, tw[(m2 * d) << 4]);
        buf[SW(base2 + (d << 4))] = v;
      }
    }
    __syncthreads();
    // T3: stride 1, stream straight to chatp
    {
      cpx a[16];
      #pragma unroll
      for (int k = 0; k < 16; k++) a[k] = buf[SW((tid << 4) + k)];
      fft16(a);
      #pragma unroll
      for (int q = 0; q < 16; q++)
        chatp[(R16[q] << 8) | tid] = a[q];
    }
  }
}

// ---------- K3: 2048-pt FFT, real-pair packed (2 channels per complex FFT),
// 256 threads, 32 KB LDS. Block = (b, p); p<4 -> channels (2p,2p+1), p=4 -> channel 8.
__global__ __launch_bounds__(256, 4) void k_fft_u(const double* Asc, const cpx* tw, cpx* U){
  __shared__ cpx buf[TN];
  int pos = threadIdx.x;                 // 0..255
  int b = blockIdx.x / 5, p = blockIdx.x % 5;
  int c0 = 2 * p;
  bool dual = (p < 4);
  const double* s0 = Asc + (((size_t)b * 9 + c0) << 11);
  const double* s1 = Asc + (((size_t)b * 9 + (dual ? c0 + 1 : c0)) << 11);
  const int R8[8] = {0,4,2,6,1,5,3,7};
  // C1: radix-8 stride 256, packed z = ch_a + i*ch_b staged directly from global
  {
    cpx a[8];
    #pragma unroll
    for (int j = 0; j < 8; j++){
      int idx = pos + (j << 8);
      a[j] = cmk(s0[idx], dual ? s1[idx] : 0.0);
    }
    fft8(a);
    #pragma unroll
    for (int q = 0; q < 8; q++){
      int k = R8[q]; cpx v = a[q];
      if (k) v = cmul(v, tw[(pos * k) << 1]);
      buf[SW(pos + (k << 8))] = v;
    }
  }
  __syncthreads();
  // wave-local: 8 segments of 256; wave w owns segments 2w, 2w+1
  int l = pos & 63;
  int ll = l & 31;
  int segb = ((((pos >> 6) << 1) + (l >> 5)) << 8);
  // CA: stride 32
  {
    int base = segb + ll;
    cpx a[8];
    #pragma unroll
    for (int j = 0; j < 8; j++) a[j] = buf[SW(base + (j << 5))];
    fft8(a);
    #pragma unroll
    for (int q = 0; q < 8; q++){
      int k = R8[q]; cpx v = a[q];
      if (k) v = cmul(v, tw[(ll * k) << 4]);
      buf[SW(base + (k << 5))] = v;
    }
  }
  wsync();
  // CB: stride 4
  {
    int base = segb + ((ll >> 2) << 5) + (ll & 3);
    cpx a[8];
    #pragma unroll
    for (int j = 0; j < 8; j++) a[j] = buf[SW(base + (j << 2))];
    fft8(a);
    #pragma unroll
    for (int q = 0; q < 8; q++){
      int k = R8[q]; cpx v = a[q];
      if (k) v = cmul(v, tw[((ll & 3) * k) << 7]);
      buf[SW(base + (k << 2))] = v;
    }
  }
  wsync();
  // CC: radix-4, stride 1 (2 groups per lane)
  {
    const int R4[4] = {0,2,1,3};
    #pragma unroll
    for (int h = 0; h < 2; h++){
      int base = segb + (((ll << 1) + h) << 2);
      cpx a4[4];
      #pragma unroll
      for (int j = 0; j < 4; j++) a4[j] = buf[SW(base + j)];
      fft4(a4);
      #pragma unroll
      for (int q = 0; q < 4; q++) buf[SW(base + R4[q])] = a4[q];
    }
  }
  __syncthreads();
  // unscramble + Hermitian unpack -> U rows c0, c0+1 (natural order, coalesced)
  cpx* dst0 = U + (((size_t)b * 9 + c0) << 11);
  cpx* dst1 = U + (((size_t)b * 9 + c0 + 1) << 11);
  #pragma unroll
  for (int ii = 0; ii < 8; ii++){
    int f = pos + (ii << 8);
    int s  = ((f & 7) << 8) + (((f >> 3) & 7) << 5) + (((f >> 6) & 7) << 2) + (f >> 9);
    int m  = (TN - f) & (TN - 1);
    int sm = ((m & 7) << 8) + (((m >> 3) & 7) << 5) + (((m >> 6) & 7) << 2) + (m >> 9);
    cpx Z = buf[SW(s)], Zm = buf[SW(sm)];
    dst0[f] = cmk(0.5 * (Z.x + Zm.x), 0.5 * (Z.y - Zm.y));          // (Z + conj(Zm))/2
    if (dual)
      dst1[f] = cmk(0.5 * (Z.y + Zm.y), 0.5 * (Zm.x - Z.x));        // (Z - conj(Zm))/(2i)
  }
}

// ---------- K4: CZT pair kernel, 256 threads, radix-16^3, BOTH e-passes FUSED.
// R0-R3 triangulation: regime is dependency-stall; ILP/thread is the only lever
// that moved dur (2 groups -> +31% vs 1). Fusing the two independent e-passes
// (Uct-path and Uc-path) restores ILP=2, halves barrier stages (10 -> 5),
// shares ALL table loads (tw/chatp/g2) between passes, and kills the pst
// round-trip. Cost: 2x 4096-cpx LDS buffers = 128 KB -> 1 block/CU (4 waves);
// wave count was proven a non-lever (R1/R2).
// R4 post-mortem: container died before grading; only risky change was 128 KB
// STATIC __shared__. Now allocated as DYNAMIC LDS with one-time
// hipFuncSetAttribute opt-in in kernel_launch (gfx950 LDS = 160 KB/CU).
__global__ __launch_bounds__(256, 1) void k_czt(const cpx* U, const cpx* HsQ, const cpx* tw,
                                                const cpx* chatp, const cpx* g2, float* Rst){
  extern __shared__ cpx dynbuf[];        // 2 * NF cpx = 128 KB, set at launch
  cpx* buf0 = dynbuf;
  cpx* buf1 = dynbuf + NF;
  int gb = blockIdx.x;
  int pair = gb & 1;
  int bc = gb >> 1;
  int b = bc / 9, c = bc % 9;
  int ct = (c % 3) * 3 + (c / 3);        // inv(A) = A^T for SO(3)
  const cpx* Us0 = U + ((size_t)b * 9 + ct) * TN;   // e=0 operand
  const cpx* Us1 = U + ((size_t)b * 9 + c)  * TN;   // e=1 operand
  const cpx* H0 = HsQ + (((pair << 1) | 0) << 11);
  const cpx* H1 = HsQ + (((pair << 1) | 1) << 11);
  int t = threadIdx.x;                   // 0..255 (= group index in every stage)
  int m = t & 15;                        // T2 pos within its 256-block
  int base2 = ((t >> 4) << 8) + m;       // T2 base (wave-local)
  int base3 = t << 4;                    // T3 base (wave-local, 16 contiguous)
  const int R16[16] = {0,8,4,12,2,10,6,14,1,9,5,13,3,11,7,15};

  cpx a[16], bb[16];
  // T1: radix-16 stride 256; staging fused, upper half (p>=2048) zero; both passes
  #pragma unroll
  for (int k = 0; k < 8; k++){
    a[k]  = cmul(Us0[t + (k << 8)], H0[t + (k << 8)]);
    bb[k] = cmul(Us1[t + (k << 8)], H1[t + (k << 8)]);
  }
  fft16h(a); fft16h(bb);
  #pragma unroll
  for (int q = 0; q < 16; q++){
    int d = R16[q];
    cpx va = a[q], vb = bb[q];
    if (d){ cpx tv = tw[t * d]; va = cmul(va, tv); vb = cmul(vb, tv); }
    buf0[SW(t + (d << 8))] = va;
    buf1[SW(t + (d << 8))] = vb;
  }
  __syncthreads();
  // T2: radix-16 stride 16 (wave-local)
  #pragma unroll
  for (int k = 0; k < 16; k++){
    a[k]  = buf0[SW(base2 + (k << 4))];
    bb[k] = buf1[SW(base2 + (k << 4))];
  }
  fft16(a); fft16(bb);
  #pragma unroll
  for (int q = 0; q < 16; q++){
    int d = R16[q];
    cpx va = a[q], vb = bb[q];
    if (d){ cpx tv = tw[(m * d) << 4]; va = cmul(va, tv); vb = cmul(vb, tv); }
    buf0[SW(base2 + (d << 4))] = va;
    buf1[SW(base2 + (d << 4))] = vb;
  }
  wsync();
  // T3 + chat + invT3 fused in registers (stride 1)
  #pragma unroll
  for (int k = 0; k < 16; k++){
    a[k]  = buf0[SW(base3 + k)];
    bb[k] = buf1[SW(base3 + k)];
  }
  fft16(a); fft16(bb);
  #pragma unroll
  for (int q = 0; q < 16; q++){
    cpx ch = chatp[(R16[q] << 8) | t];
    a[q] = cmul(a[q], ch);
    bb[q] = cmul(bb[q], ch);
  }
  ifft16(a); ifft16(bb);
  #pragma unroll
  for (int k = 0; k < 16; k++){
    buf0[SW(base3 + k)] = a[k];
    buf1[SW(base3 + k)] = bb[k];
  }
  wsync();
  // invT2 (wave-local)
  #pragma unroll
  for (int q = 0; q < 16; q++){
    int d = R16[q];
    cpx va = buf0[SW(base2 + (d << 4))];
    cpx vb = buf1[SW(base2 + (d << 4))];
    if (d){ cpx tv = tw[(m * d) << 4]; va = cmulc(va, tv); vb = cmulc(vb, tv); }
    a[q] = va; bb[q] = vb;
  }
  ifft16(a); ifft16(bb);
  #pragma unroll
  for (int k = 0; k < 16; k++){
    buf0[SW(base2 + (k << 4))] = a[k];
    buf1[SW(base2 + (k << 4))] = bb[k];
  }
  __syncthreads();
  // invT1: outputs r = t + 256j, j<8 (r < 2048); pruned ifft16h; product + g2 + store
  #pragma unroll
  for (int q = 0; q < 16; q++){
    int d = R16[q];
    cpx va = buf0[SW(t + (d << 8))];
    cpx vb = buf1[SW(t + (d << 8))];
    if (d){ cpx tv = tw[t * d]; va = cmulc(va, tv); vb = cmulc(vb, tv); }
    a[q] = va; bb[q] = vb;
  }
  ifft16h(a); ifft16h(bb);
  size_t rb = ((size_t)(pair * (NB * 9) + bc) << 11);
  #pragma unroll
  for (int j = 0; j < 8; j++){
    int r = t + (j << 8);
    cpx pr = cmul(a[j], bb[j]);
    cpx g = g2[r];
    Rst[rb + r] = (float)(pr.x * g.x - pr.y * g.y);
  }
}

// ---------- K5: combine pair partials + transpose [b][c][r] -> out[b][r][c]
__global__ __launch_bounds__(256) void k_out(const float* Rst, float* out){
  __shared__ float ld[9][513];
  int b = blockIdx.x >> 2;
  int r0 = (blockIdx.x & 3) << 9;
  for (int idx = threadIdx.x; idx < 9 * 512; idx += 256){
    int cc = idx >> 9, r = idx & 511;
    size_t o0 = ((size_t)(b * 9 + cc) << 11) + r0 + r;
    ld[cc][r] = Rst[o0] + Rst[o0 + ((size_t)(NB * 9) << 11)];
  }
  __syncthreads();
  for (int idx = threadIdx.x; idx < 512 * 9; idx += 256){
    int r = idx / 9, cc = idx - 9 * r;
    out[((size_t)b * TN + r0 + r) * 9 + cc] = ld[cc][r];
  }
}

extern "C" void kernel_launch(void* const* d_in, const int* in_sizes, int n_in,
                              void* d_out, int out_size, void* d_ws, size_t ws_size,
                              hipStream_t stream){
  const float* x  = (const float*)d_in[0];
  const float* A1 = (const float*)d_in[1];
  const float* A2 = (const float*)d_in[2];
  const float* fpar[16];
  for (int i = 0; i < 16; i++) fpar[i] = (const float*)d_in[3 + i];
  float* out = (float*)d_out;

  // one-time opt-in for 128 KB dynamic LDS on k_czt (host-side call, not a
  // stream op -> graph-capture safe; result intentionally ignored: on ROCm
  // builds where the attribute is a no-op the launch arg alone suffices)
  static bool czt_attr_done = false;
  if (!czt_attr_done){
    (void)hipFuncSetAttribute(reinterpret_cast<const void*>(k_czt),
                              hipFuncAttributeMaxDynamicSharedMemorySize,
                              2 * NF * (int)sizeof(cpx));
    czt_attr_done = true;
  }

  // workspace carve (units: doubles), total ~28.7 MB
  double* ws = (double*)d_ws;
  size_t o = 0;
  double* arr  = ws + o;         o += 4 * TN;
  cpx* HsQ     = (cpx*)(ws + o); o += 2 * 4 * TN;
  cpx* tw      = (cpx*)(ws + o); o += 2 * NF;
  cpx* chatp   = (cpx*)(ws + o); o += 2 * NF;
  cpx* Q       = (cpx*)(ws + o); o += 2 * TN;
  cpx* g2      = (cpx*)(ws + o); o += 2 * TN;
  double* Asc  = ws + o;         o += (size_t)NB * TN * 9;      // 9.4 MB
  cpx* U       = (cpx*)(ws + o); o += 2 * (size_t)NB * 9 * TN;  // 18.9 MB
  float* Rst   = (float*)Asc;    // Asc dead after k_fft_u; 2*576*2048*4B = 9.4 MB exact fit

  k_prep<<<32, 256, 0, stream>>>(fpar[0], fpar[1], fpar[2], fpar[3],
                                 fpar[4], fpar[5], fpar[6], fpar[7],
                                 fpar[8], fpar[9], fpar[10], fpar[11],
                                 fpar[12], fpar[13], fpar[14], fpar[15],
                                 arr, tw, Q, g2);
  k_front<<<321, 256, 0, stream>>>(x, A1, A2, arr, Q, tw, HsQ, Asc, chatp);
  k_fft_u<<<NB * 5, 256, 0, stream>>>(Asc, tw, U);
  k_czt<<<NB * 9 * 2, 256, 2 * NF * sizeof(cpx), stream>>>(U, HsQ, tw, chatp, g2, Rst);
  k_out<<<NB * 4, 256, 0, stream>>>(Rst, out);
}

// Round 6
// 197.864 us; speedup vs baseline: 1.2418x; 1.2418x over previous
//
#include <hip/hip_runtime.h>
#include <math.h>

#define TN 2048            // T
#define NF 4096            // Bluestein FFT length
#define NB 64              // batch
#define LF 6142LL          // L = 3T-2
#define L2F 12284LL        // 2L
#define PI_D 3.14159265358979323846264338327950288
#define C8 0.70710678118654752440084436210485
#define K16A 0.92387953251128675612818318939678828682   // cos(pi/8)
#define K16B 0.38268343236508977172845998403039886676   // sin(pi/8)

typedef double2 cpx;
typedef float2 spx;        // fp32 LDS staging element (compute stays fp64 in regs)

__device__ __forceinline__ cpx cmk(double a, double b){ cpx r; r.x=a; r.y=b; return r; }
__device__ __forceinline__ cpx cadd(cpx a, cpx b){ return cmk(a.x+b.x, a.y+b.y); }
__device__ __forceinline__ cpx csub(cpx a, cpx b){ return cmk(a.x-b.x, a.y-b.y); }
__device__ __forceinline__ cpx cmul(cpx a, cpx b){ return cmk(a.x*b.x - a.y*b.y, a.x*b.y + a.y*b.x); }
__device__ __forceinline__ cpx cmulc(cpx a, cpx b){ return cmk(a.x*b.x + a.y*b.y, a.y*b.x - a.x*b.y); } // a*conj(b)
__device__ __forceinline__ spx c2s(cpx a){ spx r; r.x=(float)a.x; r.y=(float)a.y; return r; }
__device__ __forceinline__ cpx s2c(spx a){ return cmk((double)a.x, (double)a.y); }

// LDS swizzle (element granularity, involution)
__device__ __forceinline__ int SW(int i){ return i ^ ((i >> 3) & 7) ^ ((i >> 6) & 7); }

// wave-local sync: fences compiler + drains lgkmcnt; no cross-wave lock-step
__device__ __forceinline__ void wsync(){
  __builtin_amdgcn_wave_barrier();
  asm volatile("s_waitcnt lgkmcnt(0)" ::: "memory");
  __builtin_amdgcn_wave_barrier();
}

// ---------- 8-point register FFT (DIF, natural in; reg q holds freq R8[q]={0,4,2,6,1,5,3,7})
__device__ __forceinline__ void fft8_bc(cpx* a){
  cpx u, v, d;
  u=a[0]; v=a[2]; a[0]=cadd(u,v); a[2]=csub(u,v);
  u=a[1]; v=a[3]; a[1]=cadd(u,v); d=csub(u,v); a[3]=cmk(d.y, -d.x);
  u=a[4]; v=a[6]; a[4]=cadd(u,v); a[6]=csub(u,v);
  u=a[5]; v=a[7]; a[5]=cadd(u,v); d=csub(u,v); a[7]=cmk(d.y, -d.x);
  u=a[0]; v=a[1]; a[0]=cadd(u,v); a[1]=csub(u,v);
  u=a[2]; v=a[3]; a[2]=cadd(u,v); a[3]=csub(u,v);
  u=a[4]; v=a[5]; a[4]=cadd(u,v); a[5]=csub(u,v);
  u=a[6]; v=a[7]; a[6]=cadd(u,v); a[7]=csub(u,v);
}
__device__ __forceinline__ void fft8(cpx* a){
  cpx u, v, d;
  u=a[0]; v=a[4]; a[0]=cadd(u,v); a[4]=csub(u,v);
  u=a[1]; v=a[5]; a[1]=cadd(u,v); d=csub(u,v); a[5]=cmk(C8*(d.x+d.y), C8*(d.y-d.x));
  u=a[2]; v=a[6]; a[2]=cadd(u,v); d=csub(u,v); a[6]=cmk(d.y, -d.x);
  u=a[3]; v=a[7]; a[3]=cadd(u,v); d=csub(u,v); a[7]=cmk(C8*(d.y-d.x), -C8*(d.x+d.y));
  fft8_bc(a);
}
// unscaled inverse (input in fft8 reg order, output natural, x8)
__device__ __forceinline__ void ifft8(cpx* a){
  cpx u, v, t;
  u=a[0]; v=a[1]; a[0]=cadd(u,v); a[1]=csub(u,v);
  u=a[2]; v=a[3]; a[2]=cadd(u,v); a[3]=csub(u,v);
  u=a[4]; v=a[5]; a[4]=cadd(u,v); a[5]=csub(u,v);
  u=a[6]; v=a[7]; a[6]=cadd(u,v); a[7]=csub(u,v);
  u=a[0]; v=a[2]; a[0]=cadd(u,v); a[2]=csub(u,v);
  u=a[1]; t=a[3]; v=cmk(-t.y, t.x); a[1]=cadd(u,v); a[3]=csub(u,v);
  u=a[4]; v=a[6]; a[4]=cadd(u,v); a[6]=csub(u,v);
  u=a[5]; t=a[7]; v=cmk(-t.y, t.x); a[5]=cadd(u,v); a[7]=csub(u,v);
  u=a[0]; v=a[4]; a[0]=cadd(u,v); a[4]=csub(u,v);
  u=a[1]; t=a[5]; v=cmk(C8*(t.x-t.y), C8*(t.x+t.y)); a[1]=cadd(u,v); a[5]=csub(u,v);
  u=a[2]; t=a[6]; v=cmk(-t.y, t.x); a[2]=cadd(u,v); a[6]=csub(u,v);
  u=a[3]; t=a[7]; v=cmk(-C8*(t.x+t.y), C8*(t.x-t.y)); a[3]=cadd(u,v); a[7]=csub(u,v);
}

// ---------- 16-point register FFT: W16 level (stride 8) + two fft8.
// Output reg q holds freq R16[q] = 2*R8[q&7] + (q>>3) = bitrev4(q).
__device__ __forceinline__ void fft16(cpx* a){
  cpx u, v, d;
  u=a[0]; v=a[8];  a[0]=cadd(u,v); a[8] = csub(u,v);
  u=a[1]; v=a[9];  a[1]=cadd(u,v); d=csub(u,v); a[9]  = cmk(K16A*d.x + K16B*d.y, K16A*d.y - K16B*d.x);
  u=a[2]; v=a[10]; a[2]=cadd(u,v); d=csub(u,v); a[10] = cmk(C8*(d.x+d.y), C8*(d.y-d.x));
  u=a[3]; v=a[11]; a[3]=cadd(u,v); d=csub(u,v); a[11] = cmk(K16B*d.x + K16A*d.y, K16B*d.y - K16A*d.x);
  u=a[4]; v=a[12]; a[4]=cadd(u,v); d=csub(u,v); a[12] = cmk(d.y, -d.x);
  u=a[5]; v=a[13]; a[5]=cadd(u,v); d=csub(u,v); a[13] = cmk(K16A*d.y - K16B*d.x, -(K16A*d.x + K16B*d.y));
  u=a[6]; v=a[14]; a[6]=cadd(u,v); d=csub(u,v); a[14] = cmk(C8*(d.y-d.x), -C8*(d.x+d.y));
  u=a[7]; v=a[15]; a[7]=cadd(u,v); d=csub(u,v); a[15] = cmk(K16B*d.y - K16A*d.x, -(K16A*d.y + K16B*d.x));
  fft8(a); fft8(a+8);
}
// upper-half-zero input (a[8..15] implied 0): lvl1 degenerates to a[j+8]=a[j]*W16^j
__device__ __forceinline__ void fft16h(cpx* a){
  a[8]  = a[0];
  a[9]  = cmk(K16A*a[1].x + K16B*a[1].y, K16A*a[1].y - K16B*a[1].x);
  a[10] = cmk(C8*(a[2].x+a[2].y), C8*(a[2].y-a[2].x));
  a[11] = cmk(K16B*a[3].x + K16A*a[3].y, K16B*a[3].y - K16A*a[3].x);
  a[12] = cmk(a[4].y, -a[4].x);
  a[13] = cmk(K16A*a[5].y - K16B*a[5].x, -(K16A*a[5].x + K16B*a[5].y));
  a[14] = cmk(C8*(a[6].y-a[6].x), -C8*(a[6].x+a[6].y));
  a[15] = cmk(K16B*a[7].y - K16A*a[7].x, -(K16A*a[7].y + K16B*a[7].x));
  fft8(a); fft8(a+8);
}
// unscaled inverse (input fft16 reg order, output natural, x16):
// two ifft8 (x8 each) then undo W16 level with conj twiddles.
__device__ __forceinline__ void ifft16(cpx* a){
  ifft8(a); ifft8(a+8);
  cpx t, E;
  E=a[0]; t=a[8];                                                                 a[0]=cadd(E,t); a[8] =csub(E,t);
  E=a[1]; t=cmk(K16A*a[9].x - K16B*a[9].y,  K16A*a[9].y + K16B*a[9].x);           a[1]=cadd(E,t); a[9] =csub(E,t);
  E=a[2]; t=cmk(C8*(a[10].x - a[10].y),     C8*(a[10].x + a[10].y));              a[2]=cadd(E,t); a[10]=csub(E,t);
  E=a[3]; t=cmk(K16B*a[11].x - K16A*a[11].y, K16B*a[11].y + K16A*a[11].x);        a[3]=cadd(E,t); a[11]=csub(E,t);
  E=a[4]; t=cmk(-a[12].y, a[12].x);                                               a[4]=cadd(E,t); a[12]=csub(E,t);
  E=a[5]; t=cmk(-(K16B*a[13].x) - K16A*a[13].y, K16A*a[13].x - K16B*a[13].y);     a[5]=cadd(E,t); a[13]=csub(E,t);
  E=a[6]; t=cmk(-C8*(a[14].x + a[14].y),    C8*(a[14].x - a[14].y));              a[6]=cadd(E,t); a[14]=csub(E,t);
  E=a[7]; t=cmk(-(K16A*a[15].x) - K16B*a[15].y, K16B*a[15].x - K16A*a[15].y);     a[7]=cadd(E,t); a[15]=csub(E,t);
}
// pruned: only outputs a[0..7] (skip subtract half of the W16-undo level)
__device__ __forceinline__ void ifft16h(cpx* a){
  ifft8(a); ifft8(a+8);
  cpx t;
  t=a[8];                                                                 a[0]=cadd(a[0],t);
  t=cmk(K16A*a[9].x - K16B*a[9].y,  K16A*a[9].y + K16B*a[9].x);           a[1]=cadd(a[1],t);
  t=cmk(C8*(a[10].x - a[10].y),     C8*(a[10].x + a[10].y));              a[2]=cadd(a[2],t);
  t=cmk(K16B*a[11].x - K16A*a[11].y, K16B*a[11].y + K16A*a[11].x);        a[3]=cadd(a[3],t);
  t=cmk(-a[12].y, a[12].x);                                               a[4]=cadd(a[4],t);
  t=cmk(-(K16B*a[13].x) - K16A*a[13].y, K16A*a[13].x - K16B*a[13].y);     a[5]=cadd(a[5],t);
  t=cmk(-C8*(a[14].x + a[14].y),    C8*(a[14].x - a[14].y));              a[6]=cadd(a[6],t);
  t=cmk(-(K16A*a[15].x) - K16B*a[15].y, K16B*a[15].x - K16A*a[15].y);     a[7]=cadd(a[7],t);
}
// 4-point DIF; reg q holds freq R4[q] = {0,2,1,3}
__device__ __forceinline__ void fft4(cpx* a){
  cpx u, v, d;
  u=a[0]; v=a[2]; a[0]=cadd(u,v); a[2]=csub(u,v);
  u=a[1]; v=a[3]; a[1]=cadd(u,v); d=csub(u,v); a[3]=cmk(d.y, -d.x);
  u=a[0]; v=a[1]; a[0]=cadd(u,v); a[1]=csub(u,v);
  u=a[2]; v=a[3]; a[2]=cadd(u,v); a[3]=csub(u,v);
}

// ---------- K1: filters + tables
__global__ __launch_bounds__(256) void k_prep(
    const float* fw1, const float* fb1, const float* fw2, const float* fb2,
    const float* gw1, const float* gb1, const float* gw2, const float* gb2,
    const float* pw1, const float* pb1, const float* pw2, const float* pb2,
    const float* qw1, const float* qb1, const float* qw2, const float* qb2,
    double* arr, cpx* tw, cpx* Q, cpx* g2)
{
  int gid = blockIdx.x * 256 + threadIdx.x;   // < 8192
  if (gid < 4096){
    double s, c;
    sincos(-2.0 * PI_D * (double)gid / 4096.0, &s, &c);
    tw[gid] = cmk(c, s);
  }
  if (gid < 2048){
    long long i = gid;
    double s, c;
    long long a = ((2LL * TN - 2) * i) % LF;
    long long b = (i * i) % L2F;
    long long comb = (2 * a + b) % L2F;
    sincos(PI_D * (double)comb / (double)LF, &s, &c);
    Q[gid] = cmk(c, s);
    long long a2 = ((2LL * TN - 2 + i) * (TN - 1)) % LF;
    long long comb2 = (2 * a2 + b) % L2F;
    double phi = PI_D * (double)comb2 / (double)LF;
    double scale = 1.0 / ((double)LF * (double)LF) / (4096.0 * 4096.0);
    sincos(2.0 * phi, &s, &c);
    g2[gid] = cmk(c * scale, s * scale);
  }
  int fid = gid >> 11;
  int m = gid & (TN - 1);
  const float *W1, *B1, *W2, *B2;
  if (fid == 0){ W1=fw1; B1=fb1; W2=fw2; B2=fb2; }
  else if (fid == 1){ W1=gw1; B1=gb1; W2=gw2; B2=gb2; }
  else if (fid == 2){ W1=pw1; B1=pb1; W2=pw2; B2=pb2; }
  else { W1=qw1; B1=qb1; W2=qw2; B2=qb2; }
  int s = (fid == 0 || fid == 2) ? (TN - 1 - m) : m;
  double sv = (double)s;
  double z = (double)B2[0];
  #pragma unroll
  for (int h = 0; h < 5; h++)
    z += (double)W2[h] * tanh(sv * (double)W1[h] + (double)B1[h]);
  arr[fid * TN + m] = z * exp(-5.0 * sv);
}

// ---------- SO(3) helpers
__device__ __forceinline__ void mat_mul3(double* D, const double* A, const double* B){
  double r[9];
  #pragma unroll
  for (int i = 0; i < 3; i++)
    #pragma unroll
    for (int j = 0; j < 3; j++)
      r[i*3+j] = A[i*3]*B[j] + A[i*3+1]*B[3+j] + A[i*3+2]*B[6+j];
  #pragma unroll
  for (int k = 0; k < 9; k++) D[k] = r[k];
}
__device__ __forceinline__ void rod3(double* M, const double* a1, const double* a2,
                                     double z1, double z2){
  double G[9];
  #pragma unroll
  for (int k = 0; k < 9; k++) G[k] = a1[k]*z1 + a2[k]*z2;
  double wx = G[7], wy = G[2], wz = G[3];
  double th2 = wx*wx + wy*wy + wz*wz;
  double sa, cb;
  if (th2 < 1e-12){ sa = 1.0 - th2/6.0; cb = 0.5 - th2/24.0; }
  else { double th = sqrt(th2); sa = sin(th)/th; cb = (1.0 - cos(th))/th2; }
  double w[3] = {wx, wy, wz};
  #pragma unroll
  for (int i = 0; i < 3; i++)
    #pragma unroll
    for (int j = 0; j < 3; j++){
      double v = sa * G[i*3+j] + cb * (w[i]*w[j]);
      if (i == j) v += 1.0 - cb * th2;
      M[i*3+j] = v;
    }
}

// ---------- K2 merged: blocks 0-255 = H spectra (xQ folded), 256-319 = SO(3) scan, 320 = chat
__global__ __launch_bounds__(256) void k_front(
    const float* x, const float* A1f, const float* A2f,
    const double* arr, const cpx* Q, const cpx* tw,
    cpx* HsQ, double* Asc, cpx* chatp)
{
  __shared__ double smem[8192];   // 64 KB union
  int tid = threadIdx.x;
  int bid = blockIdx.x;
  if (bid < 256){
    cpx* part = (cpx*)smem;
    int f = bid >> 6;
    int jbase = (bid & 63) * 32;
    int chunk = tid & 7;
    int jl = tid >> 3;
    long long j = jbase + jl;
    long long jj = j + TN - 1;
    double s, c;
    sincos(-2.0 * PI_D * (double)jj / (double)LF, &s, &c);
    cpx W = cmk(c, s);
    long long m0 = (long long)chunk * 256;
    long long p0 = ((m0 + TN - 1) * jj) % LF;
    sincos(-2.0 * PI_D * (double)p0 / (double)LF, &s, &c);
    cpx ph = cmk(c, s);
    const double* a = arr + f * TN;
    cpx acc = cmk(0.0, 0.0);
    for (int m = (int)m0; m < (int)m0 + 256; m++){
      double av = a[m];
      acc.x += av * ph.x;
      acc.y += av * ph.y;
      ph = cmul(ph, W);
    }
    part[tid] = acc;
    __syncthreads();
    if (chunk == 0){
      cpx tot = cmk(0.0, 0.0);
      for (int q = 0; q < 8; q++) tot = cadd(tot, part[(jl << 3) + q]);
      HsQ[f * TN + (int)j] = cmul(tot, Q[j]);
    }
  } else if (bid < 320){
    int b = bid - 256;
    double (*S)[9] = (double(*)[9])smem;
    int k = tid;
    double a1[9], a2[9];
    #pragma unroll
    for (int i = 0; i < 3; i++)
      #pragma unroll
      for (int j = 0; j < 3; j++){
        a1[i*3+j] = (double)A1f[i*3+j] - (double)A1f[j*3+i];
        a2[i*3+j] = (double)A2f[i*3+j] - (double)A2f[j*3+i];
      }
    const float* xb = x + (size_t)b * TN * 2;
    double C[9] = {1,0,0, 0,1,0, 0,0,1};
    for (int i = 0; i < 8; i++){
      int t = k * 8 + i;
      if (t >= 1){
        double M[9];
        rod3(M, a1, a2, (double)xb[2*t], (double)xb[2*t+1]);
        mat_mul3(C, C, M);
      }
    }
    #pragma unroll
    for (int q = 0; q < 9; q++) S[k][q] = C[q];
    __syncthreads();
    for (int ofs = 1; ofs < 256; ofs <<= 1){
      double Lm[9], Rm[9];
      bool act = (k >= ofs);
      if (act){
        #pragma unroll
        for (int q = 0; q < 9; q++){ Lm[q] = S[k-ofs][q]; Rm[q] = S[k][q]; }
      }
      __syncthreads();
      if (act){
        double P[9];
        mat_mul3(P, Lm, Rm);
        #pragma unroll
        for (int q = 0; q < 9; q++) S[k][q] = P[q];
      }
      __syncthreads();
    }
    double P[9];
    if (k == 0){
      P[0]=1; P[1]=0; P[2]=0; P[3]=0; P[4]=1; P[5]=0; P[6]=0; P[7]=0; P[8]=1;
    } else {
      #pragma unroll
      for (int q = 0; q < 9; q++) P[q] = S[k-1][q];
    }
    for (int i = 0; i < 8; i++){
      int t = k * 8 + i;
      if (t >= 1){
        double M[9];
        rod3(M, a1, a2, (double)xb[2*t], (double)xb[2*t+1]);
        mat_mul3(P, P, M);
      }
      #pragma unroll
      for (int q = 0; q < 9; q++)
        Asc[(((size_t)b * 9 + q) << 11) + t] = P[q];
    }
  } else {
    // ---- chat: radix-16^3 DIF of chirp (MUST match k_czt stage decomposition).
    // Stored as chatp[(digit16<<8) | group]: group = stride-1 block index.
    cpx* buf = (cpx*)smem;
    const int R16[16] = {0,8,4,12,2,10,6,14,1,9,5,13,3,11,7,15};
    for (int mq = tid; mq < NF; mq += 256){
      long long mm = (mq <= 2048) ? mq : (NF - mq);
      long long qq = (mm * mm) % L2F;
      double s, c;
      sincos(-PI_D * (double)qq / (double)LF, &s, &c);
      buf[SW(mq)] = cmk(c, s);
    }
    __syncthreads();
    // T1: stride 256
    {
      cpx a[16];
      #pragma unroll
      for (int k = 0; k < 16; k++) a[k] = buf[SW(tid + (k << 8))];
      fft16(a);
      #pragma unroll
      for (int q = 0; q < 16; q++){
        int d = R16[q]; cpx v = a[q];
        if (d) v = cmul(v, tw[tid * d]);
        buf[SW(tid + (d << 8))] = v;
      }
    }
    __syncthreads();
    // T2: stride 16
    {
      int m2 = tid & 15, base2 = ((tid >> 4) << 8) + m2;
      cpx a[16];
      #pragma unroll
      for (int k = 0; k < 16; k++) a[k] = buf[SW(base2 + (k << 4))];
      fft16(a);
      #pragma unroll
      for (int q = 0; q < 16; q++){
        int d = R16[q]; cpx v = a[q];
        if (d) v = cmul(v, tw[(m2 * d) << 4]);
        buf[SW(base2 + (d << 4))] = v;
      }
    }
    __syncthreads();
    // T3: stride 1, stream straight to chatp
    {
      cpx a[16];
      #pragma unroll
      for (int k = 0; k < 16; k++) a[k] = buf[SW((tid << 4) + k)];
      fft16(a);
      #pragma unroll
      for (int q = 0; q < 16; q++)
        chatp[(R16[q] << 8) | tid] = a[q];
    }
  }
}

// ---------- K3: 2048-pt FFT, real-pair packed (2 channels per complex FFT),
// 256 threads, 32 KB LDS. Block = (b, p); p<4 -> channels (2p,2p+1), p=4 -> channel 8.
__global__ __launch_bounds__(256, 4) void k_fft_u(const double* Asc, const cpx* tw, cpx* U){
  __shared__ cpx buf[TN];
  int pos = threadIdx.x;                 // 0..255
  int b = blockIdx.x / 5, p = blockIdx.x % 5;
  int c0 = 2 * p;
  bool dual = (p < 4);
  const double* s0 = Asc + (((size_t)b * 9 + c0) << 11);
  const double* s1 = Asc + (((size_t)b * 9 + (dual ? c0 + 1 : c0)) << 11);
  const int R8[8] = {0,4,2,6,1,5,3,7};
  // C1: radix-8 stride 256, packed z = ch_a + i*ch_b staged directly from global
  {
    cpx a[8];
    #pragma unroll
    for (int j = 0; j < 8; j++){
      int idx = pos + (j << 8);
      a[j] = cmk(s0[idx], dual ? s1[idx] : 0.0);
    }
    fft8(a);
    #pragma unroll
    for (int q = 0; q < 8; q++){
      int k = R8[q]; cpx v = a[q];
      if (k) v = cmul(v, tw[(pos * k) << 1]);
      buf[SW(pos + (k << 8))] = v;
    }
  }
  __syncthreads();
  // wave-local: 8 segments of 256; wave w owns segments 2w, 2w+1
  int l = pos & 63;
  int ll = l & 31;
  int segb = ((((pos >> 6) << 1) + (l >> 5)) << 8);
  // CA: stride 32
  {
    int base = segb + ll;
    cpx a[8];
    #pragma unroll
    for (int j = 0; j < 8; j++) a[j] = buf[SW(base + (j << 5))];
    fft8(a);
    #pragma unroll
    for (int q = 0; q < 8; q++){
      int k = R8[q]; cpx v = a[q];
      if (k) v = cmul(v, tw[(ll * k) << 4]);
      buf[SW(base + (k << 5))] = v;
    }
  }
  wsync();
  // CB: stride 4
  {
    int base = segb + ((ll >> 2) << 5) + (ll & 3);
    cpx a[8];
    #pragma unroll
    for (int j = 0; j < 8; j++) a[j] = buf[SW(base + (j << 2))];
    fft8(a);
    #pragma unroll
    for (int q = 0; q < 8; q++){
      int k = R8[q]; cpx v = a[q];
      if (k) v = cmul(v, tw[((ll & 3) * k) << 7]);
      buf[SW(base + (k << 2))] = v;
    }
  }
  wsync();
  // CC: radix-4, stride 1 (2 groups per lane)
  {
    const int R4[4] = {0,2,1,3};
    #pragma unroll
    for (int h = 0; h < 2; h++){
      int base = segb + (((ll << 1) + h) << 2);
      cpx a4[4];
      #pragma unroll
      for (int j = 0; j < 4; j++) a4[j] = buf[SW(base + j)];
      fft4(a4);
      #pragma unroll
      for (int q = 0; q < 4; q++) buf[SW(base + R4[q])] = a4[q];
    }
  }
  __syncthreads();
  // unscramble + Hermitian unpack -> U rows c0, c0+1 (natural order, coalesced)
  cpx* dst0 = U + (((size_t)b * 9 + c0) << 11);
  cpx* dst1 = U + (((size_t)b * 9 + c0 + 1) << 11);
  #pragma unroll
  for (int ii = 0; ii < 8; ii++){
    int f = pos + (ii << 8);
    int s  = ((f & 7) << 8) + (((f >> 3) & 7) << 5) + (((f >> 6) & 7) << 2) + (f >> 9);
    int m  = (TN - f) & (TN - 1);
    int sm = ((m & 7) << 8) + (((m >> 3) & 7) << 5) + (((m >> 6) & 7) << 2) + (m >> 9);
    cpx Z = buf[SW(s)], Zm = buf[SW(sm)];
    dst0[f] = cmk(0.5 * (Z.x + Zm.x), 0.5 * (Z.y - Zm.y));          // (Z + conj(Zm))/2
    if (dual)
      dst1[f] = cmk(0.5 * (Z.y + Zm.y), 0.5 * (Zm.x - Z.x));        // (Z - conj(Zm))/(2i)
  }
}

// ---------- K4: CZT pair kernel, 256 threads, radix-16^3, BOTH e-passes FUSED,
// fp32 LDS staging (compute stays fp64 in registers).
// R0-R5 dataset: need ILP=2 (R0 vs R3: +10%) AND >=8 waves/CU (R3 vs R5: 4-wave
// fusion gave back what it gained). fp64 dual buffers = 128 KB forced 1 block/CU;
// float2 staging halves them to 2 x 32 KB -> 2 blocks/CU = 8 waves WITH fusion.
// Precision: 4 LDS round-trips add ~1e-6 relative — far below the complex64
// reference's own FFT noise floor. Side benefit: ds b64 (~6cyc) vs b128 (~12cyc).
__global__ __launch_bounds__(256, 2) void k_czt(const cpx* U, const cpx* HsQ, const cpx* tw,
                                                const cpx* chatp, const cpx* g2, float* Rst){
  __shared__ spx buf0[NF];               // 32 KB
  __shared__ spx buf1[NF];               // 32 KB
  int gb = blockIdx.x;
  int pair = gb & 1;
  int bc = gb >> 1;
  int b = bc / 9, c = bc % 9;
  int ct = (c % 3) * 3 + (c / 3);        // inv(A) = A^T for SO(3)
  const cpx* Us0 = U + ((size_t)b * 9 + ct) * TN;   // e=0 operand
  const cpx* Us1 = U + ((size_t)b * 9 + c)  * TN;   // e=1 operand
  const cpx* H0 = HsQ + (((pair << 1) | 0) << 11);
  const cpx* H1 = HsQ + (((pair << 1) | 1) << 11);
  int t = threadIdx.x;                   // 0..255 (= group index in every stage)
  int m = t & 15;                        // T2 pos within its 256-block
  int base2 = ((t >> 4) << 8) + m;       // T2 base (wave-local)
  int base3 = t << 4;                    // T3 base (wave-local, 16 contiguous)
  const int R16[16] = {0,8,4,12,2,10,6,14,1,9,5,13,3,11,7,15};

  cpx a[16], bb[16];
  // T1: radix-16 stride 256; staging fused, upper half (p>=2048) zero; both passes
  #pragma unroll
  for (int k = 0; k < 8; k++){
    a[k]  = cmul(Us0[t + (k << 8)], H0[t + (k << 8)]);
    bb[k] = cmul(Us1[t + (k << 8)], H1[t + (k << 8)]);
  }
  fft16h(a); fft16h(bb);
  #pragma unroll
  for (int q = 0; q < 16; q++){
    int d = R16[q];
    cpx va = a[q], vb = bb[q];
    if (d){ cpx tv = tw[t * d]; va = cmul(va, tv); vb = cmul(vb, tv); }
    buf0[SW(t + (d << 8))] = c2s(va);
    buf1[SW(t + (d << 8))] = c2s(vb);
  }
  __syncthreads();
  // T2: radix-16 stride 16 (wave-local)
  #pragma unroll
  for (int k = 0; k < 16; k++){
    a[k]  = s2c(buf0[SW(base2 + (k << 4))]);
    bb[k] = s2c(buf1[SW(base2 + (k << 4))]);
  }
  fft16(a); fft16(bb);
  #pragma unroll
  for (int q = 0; q < 16; q++){
    int d = R16[q];
    cpx va = a[q], vb = bb[q];
    if (d){ cpx tv = tw[(m * d) << 4]; va = cmul(va, tv); vb = cmul(vb, tv); }
    buf0[SW(base2 + (d << 4))] = c2s(va);
    buf1[SW(base2 + (d << 4))] = c2s(vb);
  }
  wsync();
  // T3 + chat + invT3 fused in registers (stride 1)
  #pragma unroll
  for (int k = 0; k < 16; k++){
    a[k]  = s2c(buf0[SW(base3 + k)]);
    bb[k] = s2c(buf1[SW(base3 + k)]);
  }
  fft16(a); fft16(bb);
  #pragma unroll
  for (int q = 0; q < 16; q++){
    cpx ch = chatp[(R16[q] << 8) | t];
    a[q] = cmul(a[q], ch);
    bb[q] = cmul(bb[q], ch);
  }
  ifft16(a); ifft16(bb);
  #pragma unroll
  for (int k = 0; k < 16; k++){
    buf0[SW(base3 + k)] = c2s(a[k]);
    buf1[SW(base3 + k)] = c2s(bb[k]);
  }
  wsync();
  // invT2 (wave-local)
  #pragma unroll
  for (int q = 0; q < 16; q++){
    int d = R16[q];
    cpx va = s2c(buf0[SW(base2 + (d << 4))]);
    cpx vb = s2c(buf1[SW(base2 + (d << 4))]);
    if (d){ cpx tv = tw[(m * d) << 4]; va = cmulc(va, tv); vb = cmulc(vb, tv); }
    a[q] = va; bb[q] = vb;
  }
  ifft16(a); ifft16(bb);
  #pragma unroll
  for (int k = 0; k < 16; k++){
    buf0[SW(base2 + (k << 4))] = c2s(a[k]);
    buf1[SW(base2 + (k << 4))] = c2s(bb[k]);
  }
  __syncthreads();
  // invT1: outputs r = t + 256j, j<8 (r < 2048); pruned ifft16h; product + g2 + store
  #pragma unroll
  for (int q = 0; q < 16; q++){
    int d = R16[q];
    cpx va = s2c(buf0[SW(t + (d << 8))]);
    cpx vb = s2c(buf1[SW(t + (d << 8))]);
    if (d){ cpx tv = tw[t * d]; va = cmulc(va, tv); vb = cmulc(vb, tv); }
    a[q] = va; bb[q] = vb;
  }
  ifft16h(a); ifft16h(bb);
  size_t rb = ((size_t)(pair * (NB * 9) + bc) << 11);
  #pragma unroll
  for (int j = 0; j < 8; j++){
    int r = t + (j << 8);
    cpx pr = cmul(a[j], bb[j]);
    cpx g = g2[r];
    Rst[rb + r] = (float)(pr.x * g.x - pr.y * g.y);
  }
}

// ---------- K5: combine pair partials + transpose [b][c][r] -> out[b][r][c]
__global__ __launch_bounds__(256) void k_out(const float* Rst, float* out){
  __shared__ float ld[9][513];
  int b = blockIdx.x >> 2;
  int r0 = (blockIdx.x & 3) << 9;
  for (int idx = threadIdx.x; idx < 9 * 512; idx += 256){
    int cc = idx >> 9, r = idx & 511;
    size_t o0 = ((size_t)(b * 9 + cc) << 11) + r0 + r;
    ld[cc][r] = Rst[o0] + Rst[o0 + ((size_t)(NB * 9) << 11)];
  }
  __syncthreads();
  for (int idx = threadIdx.x; idx < 512 * 9; idx += 256){
    int r = idx / 9, cc = idx - 9 * r;
    out[((size_t)b * TN + r0 + r) * 9 + cc] = ld[cc][r];
  }
}

extern "C" void kernel_launch(void* const* d_in, const int* in_sizes, int n_in,
                              void* d_out, int out_size, void* d_ws, size_t ws_size,
                              hipStream_t stream){
  const float* x  = (const float*)d_in[0];
  const float* A1 = (const float*)d_in[1];
  const float* A2 = (const float*)d_in[2];
  const float* fpar[16];
  for (int i = 0; i < 16; i++) fpar[i] = (const float*)d_in[3 + i];
  float* out = (float*)d_out;

  // workspace carve (units: doubles), total ~28.7 MB
  double* ws = (double*)d_ws;
  size_t o = 0;
  double* arr  = ws + o;         o += 4 * TN;
  cpx* HsQ     = (cpx*)(ws + o); o += 2 * 4 * TN;
  cpx* tw      = (cpx*)(ws + o); o += 2 * NF;
  cpx* chatp   = (cpx*)(ws + o); o += 2 * NF;
  cpx* Q       = (cpx*)(ws + o); o += 2 * TN;
  cpx* g2      = (cpx*)(ws + o); o += 2 * TN;
  double* Asc  = ws + o;         o += (size_t)NB * TN * 9;      // 9.4 MB
  cpx* U       = (cpx*)(ws + o); o += 2 * (size_t)NB * 9 * TN;  // 18.9 MB
  float* Rst   = (float*)Asc;    // Asc dead after k_fft_u; 2*576*2048*4B = 9.4 MB exact fit

  k_prep<<<32, 256, 0, stream>>>(fpar[0], fpar[1], fpar[2], fpar[3],
                                 fpar[4], fpar[5], fpar[6], fpar[7],
                                 fpar[8], fpar[9], fpar[10], fpar[11],
                                 fpar[12], fpar[13], fpar[14], fpar[15],
                                 arr, tw, Q, g2);
  k_front<<<321, 256, 0, stream>>>(x, A1, A2, arr, Q, tw, HsQ, Asc, chatp);
  k_fft_u<<<NB * 5, 256, 0, stream>>>(Asc, tw, U);
  k_czt<<<NB * 9 * 2, 256, 0, stream>>>(U, HsQ, tw, chatp, g2, Rst);
  k_out<<<NB * 4, 256, 0, stream>>>(Rst, out);
}

// Round 7
// 186.275 us; speedup vs baseline: 1.3191x; 1.0622x over previous
//
#include <hip/hip_runtime.h>
#include <math.h>

#define TN 2048            // T
#define NF 4096            // Bluestein FFT length
#define NB 64              // batch
#define LF 6142LL          // L = 3T-2
#define L2F 12284LL        // 2L
#define PI_D 3.14159265358979323846264338327950288
#define C8 0.70710678118654752440084436210485
#define K16A 0.92387953251128675612818318939678828682   // cos(pi/8)
#define K16B 0.38268343236508977172845998403039886676   // sin(pi/8)
#define C8f   0.70710678118654752440f
#define K16Af 0.92387953251128675613f
#define K16Bf 0.38268343236508977173f

typedef double2 cpx;
typedef float2 cf;

__device__ __forceinline__ cpx cmk(double a, double b){ cpx r; r.x=a; r.y=b; return r; }
__device__ __forceinline__ cpx cadd(cpx a, cpx b){ return cmk(a.x+b.x, a.y+b.y); }
__device__ __forceinline__ cpx csub(cpx a, cpx b){ return cmk(a.x-b.x, a.y-b.y); }
__device__ __forceinline__ cpx cmul(cpx a, cpx b){ return cmk(a.x*b.x - a.y*b.y, a.x*b.y + a.y*b.x); }
__device__ __forceinline__ cpx cmulc(cpx a, cpx b){ return cmk(a.x*b.x + a.y*b.y, a.y*b.x - a.x*b.y); } // a*conj(b)
__device__ __forceinline__ cf c2s(cpx a){ cf r; r.x=(float)a.x; r.y=(float)a.y; return r; }

__device__ __forceinline__ cf cfmk(float a, float b){ cf r; r.x=a; r.y=b; return r; }
__device__ __forceinline__ cf cfadd(cf a, cf b){ return cfmk(a.x+b.x, a.y+b.y); }
__device__ __forceinline__ cf cfsub(cf a, cf b){ return cfmk(a.x-b.x, a.y-b.y); }
__device__ __forceinline__ cf cfmul(cf a, cf b){ return cfmk(a.x*b.x - a.y*b.y, a.x*b.y + a.y*b.x); }
__device__ __forceinline__ cf cfmulc(cf a, cf b){ return cfmk(a.x*b.x + a.y*b.y, a.y*b.x - a.x*b.y); }

// LDS swizzle, element (8 B) granularity — used by fp64 kernels (k_front/k_fft_u)
__device__ __forceinline__ int SW(int i){ return i ^ ((i >> 3) & 7) ^ ((i >> 6) & 7); }
// LDS swizzle, pair (16 B float4) granularity — k_czt. Involution (only low 4 bits
// modified); verified bank-ideal (8 dword-slots/bank) for stride 256/16/1 patterns.
__device__ __forceinline__ int SWP(int i){ return i ^ ((i >> 4) & 15) ^ ((i >> 8) & 15); }

// wave-local sync: fences compiler + drains lgkmcnt; no cross-wave lock-step
__device__ __forceinline__ void wsync(){
  __builtin_amdgcn_wave_barrier();
  asm volatile("s_waitcnt lgkmcnt(0)" ::: "memory");
  __builtin_amdgcn_wave_barrier();
}

// ---------- fp64 8-point register FFT (DIF; reg q holds freq R8[q]={0,4,2,6,1,5,3,7})
__device__ __forceinline__ void fft8_bc(cpx* a){
  cpx u, v, d;
  u=a[0]; v=a[2]; a[0]=cadd(u,v); a[2]=csub(u,v);
  u=a[1]; v=a[3]; a[1]=cadd(u,v); d=csub(u,v); a[3]=cmk(d.y, -d.x);
  u=a[4]; v=a[6]; a[4]=cadd(u,v); a[6]=csub(u,v);
  u=a[5]; v=a[7]; a[5]=cadd(u,v); d=csub(u,v); a[7]=cmk(d.y, -d.x);
  u=a[0]; v=a[1]; a[0]=cadd(u,v); a[1]=csub(u,v);
  u=a[2]; v=a[3]; a[2]=cadd(u,v); a[3]=csub(u,v);
  u=a[4]; v=a[5]; a[4]=cadd(u,v); a[5]=csub(u,v);
  u=a[6]; v=a[7]; a[6]=cadd(u,v); a[7]=csub(u,v);
}
__device__ __forceinline__ void fft8(cpx* a){
  cpx u, v, d;
  u=a[0]; v=a[4]; a[0]=cadd(u,v); a[4]=csub(u,v);
  u=a[1]; v=a[5]; a[1]=cadd(u,v); d=csub(u,v); a[5]=cmk(C8*(d.x+d.y), C8*(d.y-d.x));
  u=a[2]; v=a[6]; a[2]=cadd(u,v); d=csub(u,v); a[6]=cmk(d.y, -d.x);
  u=a[3]; v=a[7]; a[3]=cadd(u,v); d=csub(u,v); a[7]=cmk(C8*(d.y-d.x), -C8*(d.x+d.y));
  fft8_bc(a);
}
// ---------- fp64 16-point (k_front chat builder): W16 level + two fft8.
// Output reg q holds freq R16[q] = bitrev4(q).
__device__ __forceinline__ void fft16(cpx* a){
  cpx u, v, d;
  u=a[0]; v=a[8];  a[0]=cadd(u,v); a[8] = csub(u,v);
  u=a[1]; v=a[9];  a[1]=cadd(u,v); d=csub(u,v); a[9]  = cmk(K16A*d.x + K16B*d.y, K16A*d.y - K16B*d.x);
  u=a[2]; v=a[10]; a[2]=cadd(u,v); d=csub(u,v); a[10] = cmk(C8*(d.x+d.y), C8*(d.y-d.x));
  u=a[3]; v=a[11]; a[3]=cadd(u,v); d=csub(u,v); a[11] = cmk(K16B*d.x + K16A*d.y, K16B*d.y - K16A*d.x);
  u=a[4]; v=a[12]; a[4]=cadd(u,v); d=csub(u,v); a[12] = cmk(d.y, -d.x);
  u=a[5]; v=a[13]; a[5]=cadd(u,v); d=csub(u,v); a[13] = cmk(K16A*d.y - K16B*d.x, -(K16A*d.x + K16B*d.y));
  u=a[6]; v=a[14]; a[6]=cadd(u,v); d=csub(u,v); a[14] = cmk(C8*(d.y-d.x), -C8*(d.x+d.y));
  u=a[7]; v=a[15]; a[7]=cadd(u,v); d=csub(u,v); a[15] = cmk(K16B*d.y - K16A*d.x, -(K16A*d.y + K16B*d.x));
  fft8(a); fft8(a+8);
}
// fp64 4-point DIF (k_fft_u); reg q holds freq R4[q] = {0,2,1,3}
__device__ __forceinline__ void fft4(cpx* a){
  cpx u, v, d;
  u=a[0]; v=a[2]; a[0]=cadd(u,v); a[2]=csub(u,v);
  u=a[1]; v=a[3]; a[1]=cadd(u,v); d=csub(u,v); a[3]=cmk(d.y, -d.x);
  u=a[0]; v=a[1]; a[0]=cadd(u,v); a[1]=csub(u,v);
  u=a[2]; v=a[3]; a[2]=cadd(u,v); a[3]=csub(u,v);
}

// ---------- fp32 butterfly set (k_czt only; mechanical copies of the verified fp64 set)
__device__ __forceinline__ void fft8s_bc(cf* a){
  cf u, v, d;
  u=a[0]; v=a[2]; a[0]=cfadd(u,v); a[2]=cfsub(u,v);
  u=a[1]; v=a[3]; a[1]=cfadd(u,v); d=cfsub(u,v); a[3]=cfmk(d.y, -d.x);
  u=a[4]; v=a[6]; a[4]=cfadd(u,v); a[6]=cfsub(u,v);
  u=a[5]; v=a[7]; a[5]=cfadd(u,v); d=cfsub(u,v); a[7]=cfmk(d.y, -d.x);
  u=a[0]; v=a[1]; a[0]=cfadd(u,v); a[1]=cfsub(u,v);
  u=a[2]; v=a[3]; a[2]=cfadd(u,v); a[3]=cfsub(u,v);
  u=a[4]; v=a[5]; a[4]=cfadd(u,v); a[5]=cfsub(u,v);
  u=a[6]; v=a[7]; a[6]=cfadd(u,v); a[7]=cfsub(u,v);
}
__device__ __forceinline__ void fft8s(cf* a){
  cf u, v, d;
  u=a[0]; v=a[4]; a[0]=cfadd(u,v); a[4]=cfsub(u,v);
  u=a[1]; v=a[5]; a[1]=cfadd(u,v); d=cfsub(u,v); a[5]=cfmk(C8f*(d.x+d.y), C8f*(d.y-d.x));
  u=a[2]; v=a[6]; a[2]=cfadd(u,v); d=cfsub(u,v); a[6]=cfmk(d.y, -d.x);
  u=a[3]; v=a[7]; a[3]=cfadd(u,v); d=cfsub(u,v); a[7]=cfmk(C8f*(d.y-d.x), -C8f*(d.x+d.y));
  fft8s_bc(a);
}
__device__ __forceinline__ void ifft8s(cf* a){
  cf u, v, t;
  u=a[0]; v=a[1]; a[0]=cfadd(u,v); a[1]=cfsub(u,v);
  u=a[2]; v=a[3]; a[2]=cfadd(u,v); a[3]=cfsub(u,v);
  u=a[4]; v=a[5]; a[4]=cfadd(u,v); a[5]=cfsub(u,v);
  u=a[6]; v=a[7]; a[6]=cfadd(u,v); a[7]=cfsub(u,v);
  u=a[0]; v=a[2]; a[0]=cfadd(u,v); a[2]=cfsub(u,v);
  u=a[1]; t=a[3]; v=cfmk(-t.y, t.x); a[1]=cfadd(u,v); a[3]=cfsub(u,v);
  u=a[4]; v=a[6]; a[4]=cfadd(u,v); a[6]=cfsub(u,v);
  u=a[5]; t=a[7]; v=cfmk(-t.y, t.x); a[5]=cfadd(u,v); a[7]=cfsub(u,v);
  u=a[0]; v=a[4]; a[0]=cfadd(u,v); a[4]=cfsub(u,v);
  u=a[1]; t=a[5]; v=cfmk(C8f*(t.x-t.y), C8f*(t.x+t.y)); a[1]=cfadd(u,v); a[5]=cfsub(u,v);
  u=a[2]; t=a[6]; v=cfmk(-t.y, t.x); a[2]=cfadd(u,v); a[6]=cfsub(u,v);
  u=a[3]; t=a[7]; v=cfmk(-C8f*(t.x+t.y), C8f*(t.x-t.y)); a[3]=cfadd(u,v); a[7]=cfsub(u,v);
}
__device__ __forceinline__ void ffts16(cf* a){
  cf u, v, d;
  u=a[0]; v=a[8];  a[0]=cfadd(u,v); a[8] = cfsub(u,v);
  u=a[1]; v=a[9];  a[1]=cfadd(u,v); d=cfsub(u,v); a[9]  = cfmk(K16Af*d.x + K16Bf*d.y, K16Af*d.y - K16Bf*d.x);
  u=a[2]; v=a[10]; a[2]=cfadd(u,v); d=cfsub(u,v); a[10] = cfmk(C8f*(d.x+d.y), C8f*(d.y-d.x));
  u=a[3]; v=a[11]; a[3]=cfadd(u,v); d=cfsub(u,v); a[11] = cfmk(K16Bf*d.x + K16Af*d.y, K16Bf*d.y - K16Af*d.x);
  u=a[4]; v=a[12]; a[4]=cfadd(u,v); d=cfsub(u,v); a[12] = cfmk(d.y, -d.x);
  u=a[5]; v=a[13]; a[5]=cfadd(u,v); d=cfsub(u,v); a[13] = cfmk(K16Af*d.y - K16Bf*d.x, -(K16Af*d.x + K16Bf*d.y));
  u=a[6]; v=a[14]; a[6]=cfadd(u,v); d=cfsub(u,v); a[14] = cfmk(C8f*(d.y-d.x), -C8f*(d.x+d.y));
  u=a[7]; v=a[15]; a[7]=cfadd(u,v); d=cfsub(u,v); a[15] = cfmk(K16Bf*d.y - K16Af*d.x, -(K16Af*d.y + K16Bf*d.x));
  fft8s(a); fft8s(a+8);
}
__device__ __forceinline__ void ffts16h(cf* a){
  a[8]  = a[0];
  a[9]  = cfmk(K16Af*a[1].x + K16Bf*a[1].y, K16Af*a[1].y - K16Bf*a[1].x);
  a[10] = cfmk(C8f*(a[2].x+a[2].y), C8f*(a[2].y-a[2].x));
  a[11] = cfmk(K16Bf*a[3].x + K16Af*a[3].y, K16Bf*a[3].y - K16Af*a[3].x);
  a[12] = cfmk(a[4].y, -a[4].x);
  a[13] = cfmk(K16Af*a[5].y - K16Bf*a[5].x, -(K16Af*a[5].x + K16Bf*a[5].y));
  a[14] = cfmk(C8f*(a[6].y-a[6].x), -C8f*(a[6].x+a[6].y));
  a[15] = cfmk(K16Bf*a[7].y - K16Af*a[7].x, -(K16Af*a[7].y + K16Bf*a[7].x));
  fft8s(a); fft8s(a+8);
}
__device__ __forceinline__ void iffts16(cf* a){
  ifft8s(a); ifft8s(a+8);
  cf t, E;
  E=a[0]; t=a[8];                                                                   a[0]=cfadd(E,t); a[8] =cfsub(E,t);
  E=a[1]; t=cfmk(K16Af*a[9].x - K16Bf*a[9].y,  K16Af*a[9].y + K16Bf*a[9].x);        a[1]=cfadd(E,t); a[9] =cfsub(E,t);
  E=a[2]; t=cfmk(C8f*(a[10].x - a[10].y),      C8f*(a[10].x + a[10].y));            a[2]=cfadd(E,t); a[10]=cfsub(E,t);
  E=a[3]; t=cfmk(K16Bf*a[11].x - K16Af*a[11].y, K16Bf*a[11].y + K16Af*a[11].x);     a[3]=cfadd(E,t); a[11]=cfsub(E,t);
  E=a[4]; t=cfmk(-a[12].y, a[12].x);                                                a[4]=cfadd(E,t); a[12]=cfsub(E,t);
  E=a[5]; t=cfmk(-(K16Bf*a[13].x) - K16Af*a[13].y, K16Af*a[13].x - K16Bf*a[13].y);  a[5]=cfadd(E,t); a[13]=cfsub(E,t);
  E=a[6]; t=cfmk(-C8f*(a[14].x + a[14].y),     C8f*(a[14].x - a[14].y));            a[6]=cfadd(E,t); a[14]=cfsub(E,t);
  E=a[7]; t=cfmk(-(K16Af*a[15].x) - K16Bf*a[15].y, K16Bf*a[15].x - K16Af*a[15].y);  a[7]=cfadd(E,t); a[15]=cfsub(E,t);
}
__device__ __forceinline__ void iffts16h(cf* a){
  ifft8s(a); ifft8s(a+8);
  cf t;
  t=a[8];                                                                  a[0]=cfadd(a[0],t);
  t=cfmk(K16Af*a[9].x - K16Bf*a[9].y,  K16Af*a[9].y + K16Bf*a[9].x);       a[1]=cfadd(a[1],t);
  t=cfmk(C8f*(a[10].x - a[10].y),      C8f*(a[10].x + a[10].y));           a[2]=cfadd(a[2],t);
  t=cfmk(K16Bf*a[11].x - K16Af*a[11].y, K16Bf*a[11].y + K16Af*a[11].x);    a[3]=cfadd(a[3],t);
  t=cfmk(-a[12].y, a[12].x);                                               a[4]=cfadd(a[4],t);
  t=cfmk(-(K16Bf*a[13].x) - K16Af*a[13].y, K16Af*a[13].x - K16Bf*a[13].y); a[5]=cfadd(a[5],t);
  t=cfmk(-C8f*(a[14].x + a[14].y),     C8f*(a[14].x - a[14].y));           a[6]=cfadd(a[6],t);
  t=cfmk(-(K16Af*a[15].x) - K16Bf*a[15].y, K16Bf*a[15].x - K16Af*a[15].y); a[7]=cfadd(a[7],t);
}

// ---------- K1: filters + tables (adds fp32 twiddle copy for k_czt)
__global__ __launch_bounds__(256) void k_prep(
    const float* fw1, const float* fb1, const float* fw2, const float* fb2,
    const float* gw1, const float* gb1, const float* gw2, const float* gb2,
    const float* pw1, const float* pb1, const float* pw2, const float* pb2,
    const float* qw1, const float* qb1, const float* qw2, const float* qb2,
    double* arr, cpx* tw, cf* tw32, cpx* Q, cpx* g2)
{
  int gid = blockIdx.x * 256 + threadIdx.x;   // < 8192
  if (gid < 4096){
    double s, c;
    sincos(-2.0 * PI_D * (double)gid / 4096.0, &s, &c);
    tw[gid] = cmk(c, s);
    tw32[gid] = cfmk((float)c, (float)s);
  }
  if (gid < 2048){
    long long i = gid;
    double s, c;
    long long a = ((2LL * TN - 2) * i) % LF;
    long long b = (i * i) % L2F;
    long long comb = (2 * a + b) % L2F;
    sincos(PI_D * (double)comb / (double)LF, &s, &c);
    Q[gid] = cmk(c, s);
    long long a2 = ((2LL * TN - 2 + i) * (TN - 1)) % LF;
    long long comb2 = (2 * a2 + b) % L2F;
    double phi = PI_D * (double)comb2 / (double)LF;
    double scale = 1.0 / ((double)LF * (double)LF) / (4096.0 * 4096.0);
    sincos(2.0 * phi, &s, &c);
    g2[gid] = cmk(c * scale, s * scale);
  }
  int fid = gid >> 11;
  int m = gid & (TN - 1);
  const float *W1, *B1, *W2, *B2;
  if (fid == 0){ W1=fw1; B1=fb1; W2=fw2; B2=fb2; }
  else if (fid == 1){ W1=gw1; B1=gb1; W2=gw2; B2=gb2; }
  else if (fid == 2){ W1=pw1; B1=pb1; W2=pw2; B2=pb2; }
  else { W1=qw1; B1=qb1; W2=qw2; B2=qb2; }
  int s = (fid == 0 || fid == 2) ? (TN - 1 - m) : m;
  double sv = (double)s;
  double z = (double)B2[0];
  #pragma unroll
  for (int h = 0; h < 5; h++)
    z += (double)W2[h] * tanh(sv * (double)W1[h] + (double)B1[h]);
  arr[fid * TN + m] = z * exp(-5.0 * sv);
}

// ---------- SO(3) helpers
__device__ __forceinline__ void mat_mul3(double* D, const double* A, const double* B){
  double r[9];
  #pragma unroll
  for (int i = 0; i < 3; i++)
    #pragma unroll
    for (int j = 0; j < 3; j++)
      r[i*3+j] = A[i*3]*B[j] + A[i*3+1]*B[3+j] + A[i*3+2]*B[6+j];
  #pragma unroll
  for (int k = 0; k < 9; k++) D[k] = r[k];
}
__device__ __forceinline__ void rod3(double* M, const double* a1, const double* a2,
                                     double z1, double z2){
  double G[9];
  #pragma unroll
  for (int k = 0; k < 9; k++) G[k] = a1[k]*z1 + a2[k]*z2;
  double wx = G[7], wy = G[2], wz = G[3];
  double th2 = wx*wx + wy*wy + wz*wz;
  double sa, cb;
  if (th2 < 1e-12){ sa = 1.0 - th2/6.0; cb = 0.5 - th2/24.0; }
  else { double th = sqrt(th2); sa = sin(th)/th; cb = (1.0 - cos(th))/th2; }
  double w[3] = {wx, wy, wz};
  #pragma unroll
  for (int i = 0; i < 3; i++)
    #pragma unroll
    for (int j = 0; j < 3; j++){
      double v = sa * G[i*3+j] + cb * (w[i]*w[j]);
      if (i == j) v += 1.0 - cb * th2;
      M[i*3+j] = v;
    }
}

// ---------- K2 merged: blocks 0-255 = H spectra (xQ folded), 256-319 = SO(3) scan, 320 = chat
__global__ __launch_bounds__(256) void k_front(
    const float* x, const float* A1f, const float* A2f,
    const double* arr, const cpx* Q, const cpx* tw,
    cf* HsQ, double* Asc, cf* chatp)
{
  __shared__ double smem[8192];   // 64 KB union
  int tid = threadIdx.x;
  int bid = blockIdx.x;
  if (bid < 256){
    cpx* part = (cpx*)smem;
    int f = bid >> 6;
    int jbase = (bid & 63) * 32;
    int chunk = tid & 7;
    int jl = tid >> 3;
    long long j = jbase + jl;
    long long jj = j + TN - 1;
    double s, c;
    sincos(-2.0 * PI_D * (double)jj / (double)LF, &s, &c);
    cpx W = cmk(c, s);
    long long m0 = (long long)chunk * 256;
    long long p0 = ((m0 + TN - 1) * jj) % LF;
    sincos(-2.0 * PI_D * (double)p0 / (double)LF, &s, &c);
    cpx ph = cmk(c, s);
    const double* a = arr + f * TN;
    cpx acc = cmk(0.0, 0.0);
    for (int m = (int)m0; m < (int)m0 + 256; m++){
      double av = a[m];
      acc.x += av * ph.x;
      acc.y += av * ph.y;
      ph = cmul(ph, W);
    }
    part[tid] = acc;
    __syncthreads();
    if (chunk == 0){
      cpx tot = cmk(0.0, 0.0);
      for (int q = 0; q < 8; q++) tot = cadd(tot, part[(jl << 3) + q]);
      HsQ[f * TN + (int)j] = c2s(cmul(tot, Q[j]));
    }
  } else if (bid < 320){
    int b = bid - 256;
    double (*S)[9] = (double(*)[9])smem;
    int k = tid;
    double a1[9], a2[9];
    #pragma unroll
    for (int i = 0; i < 3; i++)
      #pragma unroll
      for (int j = 0; j < 3; j++){
        a1[i*3+j] = (double)A1f[i*3+j] - (double)A1f[j*3+i];
        a2[i*3+j] = (double)A2f[i*3+j] - (double)A2f[j*3+i];
      }
    const float* xb = x + (size_t)b * TN * 2;
    double C[9] = {1,0,0, 0,1,0, 0,0,1};
    for (int i = 0; i < 8; i++){
      int t = k * 8 + i;
      if (t >= 1){
        double M[9];
        rod3(M, a1, a2, (double)xb[2*t], (double)xb[2*t+1]);
        mat_mul3(C, C, M);
      }
    }
    #pragma unroll
    for (int q = 0; q < 9; q++) S[k][q] = C[q];
    __syncthreads();
    for (int ofs = 1; ofs < 256; ofs <<= 1){
      double Lm[9], Rm[9];
      bool act = (k >= ofs);
      if (act){
        #pragma unroll
        for (int q = 0; q < 9; q++){ Lm[q] = S[k-ofs][q]; Rm[q] = S[k][q]; }
      }
      __syncthreads();
      if (act){
        double P[9];
        mat_mul3(P, Lm, Rm);
        #pragma unroll
        for (int q = 0; q < 9; q++) S[k][q] = P[q];
      }
      __syncthreads();
    }
    double P[9];
    if (k == 0){
      P[0]=1; P[1]=0; P[2]=0; P[3]=0; P[4]=1; P[5]=0; P[6]=0; P[7]=0; P[8]=1;
    } else {
      #pragma unroll
      for (int q = 0; q < 9; q++) P[q] = S[k-1][q];
    }
    for (int i = 0; i < 8; i++){
      int t = k * 8 + i;
      if (t >= 1){
        double M[9];
        rod3(M, a1, a2, (double)xb[2*t], (double)xb[2*t+1]);
        mat_mul3(P, P, M);
      }
      #pragma unroll
      for (int q = 0; q < 9; q++)
        Asc[(((size_t)b * 9 + q) << 11) + t] = P[q];
    }
  } else {
    // ---- chat: radix-16^3 DIF of chirp (MUST match k_czt stage decomposition).
    // Built in fp64, stored fp32 as chatp[(digit16<<8) | group].
    cpx* buf = (cpx*)smem;
    const int R16[16] = {0,8,4,12,2,10,6,14,1,9,5,13,3,11,7,15};
    for (int mq = tid; mq < NF; mq += 256){
      long long mm = (mq <= 2048) ? mq : (NF - mq);
      long long qq = (mm * mm) % L2F;
      double s, c;
      sincos(-PI_D * (double)qq / (double)LF, &s, &c);
      buf[SW(mq)] = cmk(c, s);
    }
    __syncthreads();
    // T1: stride 256
    {
      cpx a[16];
      #pragma unroll
      for (int k = 0; k < 16; k++) a[k] = buf[SW(tid + (k << 8))];
      fft16(a);
      #pragma unroll
      for (int q = 0; q < 16; q++){
        int d = R16[q]; cpx v = a[q];
        if (d) v = cmul(v, tw[tid * d]);
        buf[SW(tid + (d << 8))] = v;
      }
    }
    __syncthreads();
    // T2: stride 16
    {
      int m2 = tid & 15, base2 = ((tid >> 4) << 8) + m2;
      cpx a[16];
      #pragma unroll
      for (int k = 0; k < 16; k++) a[k] = buf[SW(base2 + (k << 4))];
      fft16(a);
      #pragma unroll
      for (int q = 0; q < 16; q++){
        int d = R16[q]; cpx v = a[q];
        if (d) v = cmul(v, tw[(m2 * d) << 4]);
        buf[SW(base2 + (d << 4))] = v;
      }
    }
    __syncthreads();
    // T3: stride 1, stream straight to chatp (fp32)
    {
      cpx a[16];
      #pragma unroll
      for (int k = 0; k < 16; k++) a[k] = buf[SW((tid << 4) + k)];
      fft16(a);
      #pragma unroll
      for (int q = 0; q < 16; q++)
        chatp[(R16[q] << 8) | tid] = c2s(a[q]);
    }
  }
}

// ---------- K3: 2048-pt FFT, real-pair packed; fp64 compute, fp32 U output
// (halves write traffic; k_czt consumes fp32). 256 threads, 32 KB LDS.
__global__ __launch_bounds__(256, 4) void k_fft_u(const double* Asc, const cpx* tw, cf* U){
  __shared__ cpx buf[TN];
  int pos = threadIdx.x;                 // 0..255
  int b = blockIdx.x / 5, p = blockIdx.x % 5;
  int c0 = 2 * p;
  bool dual = (p < 4);
  const double* s0 = Asc + (((size_t)b * 9 + c0) << 11);
  const double* s1 = Asc + (((size_t)b * 9 + (dual ? c0 + 1 : c0)) << 11);
  const int R8[8] = {0,4,2,6,1,5,3,7};
  // C1: radix-8 stride 256, packed z = ch_a + i*ch_b staged directly from global
  {
    cpx a[8];
    #pragma unroll
    for (int j = 0; j < 8; j++){
      int idx = pos + (j << 8);
      a[j] = cmk(s0[idx], dual ? s1[idx] : 0.0);
    }
    fft8(a);
    #pragma unroll
    for (int q = 0; q < 8; q++){
      int k = R8[q]; cpx v = a[q];
      if (k) v = cmul(v, tw[(pos * k) << 1]);
      buf[SW(pos + (k << 8))] = v;
    }
  }
  __syncthreads();
  // wave-local: 8 segments of 256; wave w owns segments 2w, 2w+1
  int l = pos & 63;
  int ll = l & 31;
  int segb = ((((pos >> 6) << 1) + (l >> 5)) << 8);
  // CA: stride 32
  {
    int base = segb + ll;
    cpx a[8];
    #pragma unroll
    for (int j = 0; j < 8; j++) a[j] = buf[SW(base + (j << 5))];
    fft8(a);
    #pragma unroll
    for (int q = 0; q < 8; q++){
      int k = R8[q]; cpx v = a[q];
      if (k) v = cmul(v, tw[(ll * k) << 4]);
      buf[SW(base + (k << 5))] = v;
    }
  }
  wsync();
  // CB: stride 4
  {
    int base = segb + ((ll >> 2) << 5) + (ll & 3);
    cpx a[8];
    #pragma unroll
    for (int j = 0; j < 8; j++) a[j] = buf[SW(base + (j << 2))];
    fft8(a);
    #pragma unroll
    for (int q = 0; q < 8; q++){
      int k = R8[q]; cpx v = a[q];
      if (k) v = cmul(v, tw[((ll & 3) * k) << 7]);
      buf[SW(base + (k << 2))] = v;
    }
  }
  wsync();
  // CC: radix-4, stride 1 (2 groups per lane)
  {
    const int R4[4] = {0,2,1,3};
    #pragma unroll
    for (int h = 0; h < 2; h++){
      int base = segb + (((ll << 1) + h) << 2);
      cpx a4[4];
      #pragma unroll
      for (int j = 0; j < 4; j++) a4[j] = buf[SW(base + j)];
      fft4(a4);
      #pragma unroll
      for (int q = 0; q < 4; q++) buf[SW(base + R4[q])] = a4[q];
    }
  }
  __syncthreads();
  // unscramble + Hermitian unpack -> U rows c0, c0+1 (natural order, coalesced, fp32)
  cf* dst0 = U + (((size_t)b * 9 + c0) << 11);
  cf* dst1 = U + (((size_t)b * 9 + c0 + 1) << 11);
  #pragma unroll
  for (int ii = 0; ii < 8; ii++){
    int f = pos + (ii << 8);
    int s  = ((f & 7) << 8) + (((f >> 3) & 7) << 5) + (((f >> 6) & 7) << 2) + (f >> 9);
    int m  = (TN - f) & (TN - 1);
    int sm = ((m & 7) << 8) + (((m >> 3) & 7) << 5) + (((m >> 6) & 7) << 2) + (m >> 9);
    cpx Z = buf[SW(s)], Zm = buf[SW(sm)];
    dst0[f] = c2s(cmk(0.5 * (Z.x + Zm.x), 0.5 * (Z.y - Zm.y)));     // (Z + conj(Zm))/2
    if (dual)
      dst1[f] = c2s(cmk(0.5 * (Z.y + Zm.y), 0.5 * (Zm.x - Z.x)));   // (Z - conj(Zm))/(2i)
  }
}

// ---------- K4: CZT pair kernel — FULL fp32 compute, pair-interleaved float4 LDS.
// R6 confirmed the structure (fused e-passes, ILP=2, 8 waves/CU, 64.4 us) with
// VALU-issue ~25 us (fp64) + LDS-issue ~11 us (256 b64/thread) + stalls. This
// round: (a) f32 registers halve VALU issue (2cyc vs 4cyc wave64); (b) both
// streams stored as ONE float4 per position -> 128 b128 ops/thread (half the
// LDS instructions/addressing); (c) fp32 tw/chat tables (L1/L2-hot). Final
// product + g2 stay fp64. Precision: fp32 CZT adds ~1-2e-6 rel (sqrt-growth),
// vs reference's own complex64 FFT noise (current absmax 3e-5 = 2^-15 quantum).
__global__ __launch_bounds__(256, 2) void k_czt(const cf* U, const cf* HsQ, const cf* tw32,
                                                const cf* chatp, const cpx* g2, float* Rst){
  __shared__ float4 bufp[NF];            // 64 KB: {a.re, a.im, b.re, b.im} per position
  int gb = blockIdx.x;
  int pair = gb & 1;
  int bc = gb >> 1;
  int b = bc / 9, c = bc % 9;
  int ct = (c % 3) * 3 + (c / 3);        // inv(A) = A^T for SO(3)
  const cf* Us0 = U + ((size_t)b * 9 + ct) * TN;   // e=0 operand
  const cf* Us1 = U + ((size_t)b * 9 + c)  * TN;   // e=1 operand
  const cf* H0 = HsQ + ((size_t)(pair << 1) << 11);
  const cf* H1 = HsQ + ((size_t)((pair << 1) | 1) << 11);
  int t = threadIdx.x;                   // 0..255 (= group index in every stage)
  int m = t & 15;                        // T2 pos within its 256-block
  int base2 = ((t >> 4) << 8) + m;       // T2 base (wave-local)
  int base3 = t << 4;                    // T3 base (wave-local, 16 contiguous)
  const int R16[16] = {0,8,4,12,2,10,6,14,1,9,5,13,3,11,7,15};

  cf a[16], bb[16];
  // T1: radix-16 stride 256; staging fused, upper half (p>=2048) zero; both passes
  #pragma unroll
  for (int k = 0; k < 8; k++){
    a[k]  = cfmul(Us0[t + (k << 8)], H0[t + (k << 8)]);
    bb[k] = cfmul(Us1[t + (k << 8)], H1[t + (k << 8)]);
  }
  ffts16h(a); ffts16h(bb);
  #pragma unroll
  for (int q = 0; q < 16; q++){
    int d = R16[q];
    cf va = a[q], vb = bb[q];
    if (d){ cf tv = tw32[t * d]; va = cfmul(va, tv); vb = cfmul(vb, tv); }
    bufp[SWP(t + (d << 8))] = make_float4(va.x, va.y, vb.x, vb.y);
  }
  __syncthreads();
  // T2: radix-16 stride 16 (wave-local)
  #pragma unroll
  for (int k = 0; k < 16; k++){
    float4 p = bufp[SWP(base2 + (k << 4))];
    a[k]  = cfmk(p.x, p.y);
    bb[k] = cfmk(p.z, p.w);
  }
  ffts16(a); ffts16(bb);
  #pragma unroll
  for (int q = 0; q < 16; q++){
    int d = R16[q];
    cf va = a[q], vb = bb[q];
    if (d){ cf tv = tw32[(m * d) << 4]; va = cfmul(va, tv); vb = cfmul(vb, tv); }
    bufp[SWP(base2 + (d << 4))] = make_float4(va.x, va.y, vb.x, vb.y);
  }
  wsync();
  // T3 + chat + invT3 fused in registers (stride 1)
  #pragma unroll
  for (int k = 0; k < 16; k++){
    float4 p = bufp[SWP(base3 + k)];
    a[k]  = cfmk(p.x, p.y);
    bb[k] = cfmk(p.z, p.w);
  }
  ffts16(a); ffts16(bb);
  #pragma unroll
  for (int q = 0; q < 16; q++){
    cf ch = chatp[(R16[q] << 8) | t];
    a[q] = cfmul(a[q], ch);
    bb[q] = cfmul(bb[q], ch);
  }
  iffts16(a); iffts16(bb);
  #pragma unroll
  for (int k = 0; k < 16; k++)
    bufp[SWP(base3 + k)] = make_float4(a[k].x, a[k].y, bb[k].x, bb[k].y);
  wsync();
  // invT2 (wave-local)
  #pragma unroll
  for (int q = 0; q < 16; q++){
    int d = R16[q];
    float4 p = bufp[SWP(base2 + (d << 4))];
    cf va = cfmk(p.x, p.y), vb = cfmk(p.z, p.w);
    if (d){ cf tv = tw32[(m * d) << 4]; va = cfmulc(va, tv); vb = cfmulc(vb, tv); }
    a[q] = va; bb[q] = vb;
  }
  iffts16(a); iffts16(bb);
  #pragma unroll
  for (int k = 0; k < 16; k++)
    bufp[SWP(base2 + (k << 4))] = make_float4(a[k].x, a[k].y, bb[k].x, bb[k].y);
  __syncthreads();
  // invT1: outputs r = t + 256j, j<8 (r < 2048); pruned iffts16h; product (fp64) + g2 + store
  #pragma unroll
  for (int q = 0; q < 16; q++){
    int d = R16[q];
    float4 p = bufp[SWP(t + (d << 8))];
    cf va = cfmk(p.x, p.y), vb = cfmk(p.z, p.w);
    if (d){ cf tv = tw32[t * d]; va = cfmulc(va, tv); vb = cfmulc(vb, tv); }
    a[q] = va; bb[q] = vb;
  }
  iffts16h(a); iffts16h(bb);
  size_t rb = ((size_t)(pair * (NB * 9) + bc) << 11);
  #pragma unroll
  for (int j = 0; j < 8; j++){
    int r = t + (j << 8);
    double ax = (double)a[j].x, ay = (double)a[j].y;
    double bx = (double)bb[j].x, by = (double)bb[j].y;
    double prx = ax * bx - ay * by;
    double pry = ax * by + ay * bx;
    cpx g = g2[r];
    Rst[rb + r] = (float)(prx * g.x - pry * g.y);
  }
}

// ---------- K5: combine pair partials + transpose [b][c][r] -> out[b][r][c]
__global__ __launch_bounds__(256) void k_out(const float* Rst, float* out){
  __shared__ float ld[9][513];
  int b = blockIdx.x >> 2;
  int r0 = (blockIdx.x & 3) << 9;
  for (int idx = threadIdx.x; idx < 9 * 512; idx += 256){
    int cc = idx >> 9, r = idx & 511;
    size_t o0 = ((size_t)(b * 9 + cc) << 11) + r0 + r;
    ld[cc][r] = Rst[o0] + Rst[o0 + ((size_t)(NB * 9) << 11)];
  }
  __syncthreads();
  for (int idx = threadIdx.x; idx < 512 * 9; idx += 256){
    int r = idx / 9, cc = idx - 9 * r;
    out[((size_t)b * TN + r0 + r) * 9 + cc] = ld[cc][r];
  }
}

extern "C" void kernel_launch(void* const* d_in, const int* in_sizes, int n_in,
                              void* d_out, int out_size, void* d_ws, size_t ws_size,
                              hipStream_t stream){
  const float* x  = (const float*)d_in[0];
  const float* A1 = (const float*)d_in[1];
  const float* A2 = (const float*)d_in[2];
  const float* fpar[16];
  for (int i = 0; i < 16; i++) fpar[i] = (const float*)d_in[3 + i];
  float* out = (float*)d_out;

  // workspace carve (units: doubles; cf = 1 double-slot), total ~19 MB
  double* ws = (double*)d_ws;
  size_t o = 0;
  double* arr  = ws + o;         o += 4 * TN;
  cf* HsQ      = (cf*)(ws + o);  o += 4 * TN;                    // 4 rows x TN, fp32
  cpx* tw      = (cpx*)(ws + o); o += 2 * NF;                    // fp64 (k_front/k_fft_u)
  cf* tw32     = (cf*)(ws + o);  o += NF;                        // fp32 (k_czt)
  cf* chatp    = (cf*)(ws + o);  o += NF;                        // fp32 (k_czt)
  cpx* Q       = (cpx*)(ws + o); o += 2 * TN;
  cpx* g2      = (cpx*)(ws + o); o += 2 * TN;
  double* Asc  = ws + o;         o += (size_t)NB * TN * 9;       // 9.4 MB
  cf* U        = (cf*)(ws + o);  o += (size_t)NB * 9 * TN;       // 9.4 MB (fp32)
  float* Rst   = (float*)Asc;    // Asc dead after k_fft_u; 2*576*2048*4B = 9.4 MB exact fit

  k_prep<<<32, 256, 0, stream>>>(fpar[0], fpar[1], fpar[2], fpar[3],
                                 fpar[4], fpar[5], fpar[6], fpar[7],
                                 fpar[8], fpar[9], fpar[10], fpar[11],
                                 fpar[12], fpar[13], fpar[14], fpar[15],
                                 arr, tw, tw32, Q, g2);
  k_front<<<321, 256, 0, stream>>>(x, A1, A2, arr, Q, tw, HsQ, Asc, chatp);
  k_fft_u<<<NB * 5, 256, 0, stream>>>(Asc, tw, U);
  k_czt<<<NB * 9 * 2, 256, 0, stream>>>(U, HsQ, tw32, chatp, g2, Rst);
  k_out<<<NB * 4, 256, 0, stream>>>(Rst, out);
}